// Round 5
// baseline (567.940 us; speedup 1.0000x reference)
//
#include <hip/hip_runtime.h>
#include <hip/hip_bf16.h>

#define NN 131072   // nodes per side
#define NE 524288   // edges per side
#define NB 1024     // batch (graphs per side)

typedef __attribute__((ext_vector_type(8))) short short8;   // 8 bf16
typedef __attribute__((ext_vector_type(4))) float f32x4;

__device__ __forceinline__ float wsum(float v){
#pragma unroll
  for (int o = 32; o > 0; o >>= 1) v += __shfl_xor(v, o, 64);
  return v;
}
__device__ __forceinline__ short f2bs(float f){
  __hip_bfloat16 t = __float2bfloat16(f);
  union { __hip_bfloat16 b; short s; } u; u.b = t; return u.s;
}
__device__ __forceinline__ float bs2f(short s){
  return __uint_as_float(((unsigned)(unsigned short)s) << 16);
}
__device__ __forceinline__ float ulo2f(unsigned v){ return __uint_as_float(v << 16); }
__device__ __forceinline__ float uhi2f(unsigned v){ return __uint_as_float(v & 0xFFFF0000u); }
__device__ __forceinline__ unsigned fpack(float x, float y){
  return (unsigned)(unsigned short)f2bs(x) | ((unsigned)(unsigned short)f2bs(y) << 16);
}

// ---------------- CSR build (both sides; global node = side*NN + n) ----------------
__global__ void k_zero(int* __restrict__ p){
  p[blockIdx.x * 256 + threadIdx.x] = 0;
}

__global__ void k_hist(const int* __restrict__ u_ei, const int* __restrict__ i_ei,
                       int* __restrict__ cnt){
  int ee = blockIdx.x * 256 + threadIdx.x;       // [0, 2NE)
  int side = ee >= NE;
  int e = ee - side * NE;
  const int* ei = side ? i_ei : u_ei;
  atomicAdd(&cnt[ei[NE + e] + side * NN], 1);
}

__global__ void k_scan1(const int* __restrict__ cnt, int* __restrict__ rowptr,
                        int* __restrict__ bsum){
  __shared__ int sh[256];
  int i = blockIdx.x * 256 + threadIdx.x;
  int v = cnt[i];
  sh[threadIdx.x] = v; __syncthreads();
  for (int off = 1; off < 256; off <<= 1){
    int t = (threadIdx.x >= off) ? sh[threadIdx.x - off] : 0;
    __syncthreads();
    sh[threadIdx.x] += t;
    __syncthreads();
  }
  int incl = sh[threadIdx.x];
  rowptr[i] = incl - v;
  if (threadIdx.x == 255) bsum[blockIdx.x] = incl;
}

__global__ void k_scan2(int* __restrict__ bsum){
  __shared__ int sh[1024];
  int v = bsum[threadIdx.x];
  sh[threadIdx.x] = v; __syncthreads();
  for (int off = 1; off < 1024; off <<= 1){
    int t = (threadIdx.x >= off) ? sh[threadIdx.x - off] : 0;
    __syncthreads();
    sh[threadIdx.x] += t;
    __syncthreads();
  }
  bsum[threadIdx.x] = sh[threadIdx.x] - v;  // exclusive
}

__global__ void k_scan3(int* __restrict__ rowptr, const int* __restrict__ bsum,
                        int* __restrict__ cursor){
  int i = blockIdx.x * 256 + threadIdx.x;
  int v = rowptr[i] + bsum[blockIdx.x];
  rowptr[i] = v;
  cursor[i] = v;
  if (i == 0) rowptr[2 * NN] = 2 * NE;
}

__global__ void k_scatter(const int* __restrict__ u_ei, const int* __restrict__ i_ei,
                          const int* __restrict__ u_et, const int* __restrict__ i_et,
                          int* __restrict__ cursor, int* __restrict__ pedge){
  int ee = blockIdx.x * 256 + threadIdx.x;
  int side = ee >= NE;
  int e = ee - side * NE;
  const int* ei = side ? i_ei : u_ei;
  const int* et = side ? i_et : u_et;
  int src = ei[e] + side * NN;
  int dst = ei[NE + e] + side * NN;
  int p = atomicAdd(&cursor[dst], 1);
  pedge[p] = src | (et[e] << 18);
}

// ---------------- feature gather: word_emb fp32 -> bf16 X (both sides) ----------------
__global__ void k_gather(const int* __restrict__ u_nodes, const int* __restrict__ i_nodes,
                         const float* __restrict__ wemb, unsigned* __restrict__ x32){
  int id = blockIdx.x * 256 + threadIdx.x;       // [0, 2NN*32)
  int n = id >> 5, c2 = id & 31;
  int side = n >= NN;
  int local = n - side * NN;
  int widx = (side ? i_nodes : u_nodes)[local];
  const float2* src = (const float2*)(wemb + (long)widx * 64);
  float2 v = src[c2];
  x32[id] = fpack(v.x, v.y);
}

// ---------------- weight prep: MFMA B-frags for 5 matrices + waA/ba/rtab both sides ----------------
__global__ void k_wprep(const float* __restrict__ cuW, const float* __restrict__ ciW,
                        const float* __restrict__ pW,
                        const float* __restrict__ cub, const float* __restrict__ cib,
                        const float* __restrict__ uatt, const float* __restrict__ iatt,
                        const float* __restrict__ urel, const float* __restrict__ irel,
                        short8* __restrict__ frag, float* __restrict__ waA,
                        float* __restrict__ ba, float* __restrict__ rtab){
  int blk = blockIdx.x, tid = threadIdx.x;
  if (blk < 10){
    // frag[mat*512 + ((t*2+hh)*64 + lane)][j] = bf16( W[k=hh*32+(lane>>4)*8+j][n=t*16+(lane&15)] )
    int mat = blk >> 1;
    const float* W = mat < 2 ? cuW + mat * 4096 : (mat < 4 ? ciW + (mat - 2) * 4096 : pW);
    int g = (blk & 1) * 256 + tid;     // [0,512)
    int lane = g & 63, rest = g >> 6;
    int hh = rest & 1, t = rest >> 1;
    int m = lane & 15, q = lane >> 4;
    short8 v;
#pragma unroll
    for (int j = 0; j < 8; j++)
      v[j] = f2bs(W[(hh * 32 + q * 8 + j) * 64 + (t * 16 + m)]);
    frag[mat * 512 + g] = v;
  } else {
    int side = blk - 10;
    const float* W    = side ? ciW : cuW;
    const float* bias = side ? cib : cub;
    const float* att  = side ? iatt : uatt;
    const float* rel  = side ? irel : urel;
    int l = tid >> 7, a = (tid >> 6) & 1, kk = tid & 63;
    float s = 0.f;
    for (int c = 0; c < 64; c++) s += W[l * 4096 + kk * 64 + c] * att[l * 192 + a * 64 + c];
    waA[((side * 2 + l) * 2 + a) * 64 + kk] = s;
    if (tid < 4){
      int l2 = tid >> 1, a2 = tid & 1;
      float sb = 0.f;
      for (int c = 0; c < 64; c++) sb += bias[l2 * 64 + c] * att[l2 * 192 + a2 * 64 + c];
      ba[(side * 2 + l2) * 2 + a2] = sb;
    }
    if (tid >= 4 && tid < 12){
      int id = tid - 4, l2 = id >> 2, tt = id & 3;
      float sr = 0.f;
      for (int c = 0; c < 64; c++) sr += rel[l2 * 256 + tt * 64 + c] * att[l2 * 192 + 128 + c];
      rtab[(side * 2 + l2) * 4 + tt] = sr;
    }
  }
}

// ---------------- per-interaction prep: rep (inter) + queries (both sides) ----------------
__global__ void k_prep(const int* __restrict__ uid, const int* __restrict__ iid,
                       const float* __restrict__ uemb, const float* __restrict__ iemb,
                       const float* __restrict__ uiW, const float* __restrict__ uib,
                       const float* __restrict__ iiW, const float* __restrict__ iib,
                       const float* __restrict__ utW, const float* __restrict__ utb,
                       const float* __restrict__ itW, const float* __restrict__ itb,
                       float* __restrict__ xfm, float* __restrict__ q){
  int lane = threadIdx.x & 63, w = threadIdx.x >> 6;
  int b = blockIdx.x * 4 + w;                     // [0, 2NB)
  int side = b >= NB;
  int lb = b - side * NB;
  const int* ids = side ? iid : uid;
  const float* emb = side ? iemb : uemb;
  const float* interW = side ? iiW : uiW;
  const float* interB = side ? iib : uib;
  const float* transW = side ? itW : utW;
  const float* transB = side ? itb : utb;
  int repOff = side ? 192 : 0;
  float xe = emb[(long)ids[lb] * 64 + lane];
  float o = interB[lane];
#pragma unroll
  for (int k = 0; k < 64; k++) o += __shfl(xe, k, 64) * interW[k * 64 + lane];
  xfm[lb * 384 + repOff + lane] = fmaxf(o, 0.f);
  for (int l = 0; l < 2; l++){
    float t = transB[l * 64 + lane];
#pragma unroll
    for (int k = 0; k < 64; k++) t += __shfl(xe, k, 64) * transW[l * 4096 + k * 64 + lane];
    q[((size_t)(side * 2 + l) * NB + lb) * 64 + lane] = fmaxf(t, 0.f);
  }
}

// ---------------- MFMA: h = x @ W + b (bf16 out) ; fused a0/a1 = x.waA + ba ----------------
__global__ __launch_bounds__(256) void k_gemm_h(
    const short* __restrict__ x, const short8* __restrict__ cfrag,
    const float* __restrict__ cub, const float* __restrict__ cib, int l,
    const float* __restrict__ waA_all, const float* __restrict__ ba_all,
    short* __restrict__ h, float* __restrict__ a0, float* __restrict__ a1){
  int bid = blockIdx.x;
  int side = bid >= (NN / 128);
  const short8* wfrag = cfrag + (side * 2 + l) * 512;
  const float* bias = (side ? cib : cub) + l * 64;
  const float* waA = waA_all + (side * 2 + l) * 128;
  const float* ba = ba_all + (side * 2 + l) * 2;
  int lane = threadIdx.x & 63, w = threadIdx.x >> 6;
  int m = lane & 15, q = lane >> 4;
  short8 Bf[4][2];
#pragma unroll
  for (int t = 0; t < 4; t++)
#pragma unroll
    for (int hh = 0; hh < 2; hh++)
      Bf[t][hh] = wfrag[(t * 2 + hh) * 64 + lane];
  float bs[4];
#pragma unroll
  for (int t = 0; t < 4; t++) bs[t] = bias[t * 16 + m];
  float w0[16], w1[16];
#pragma unroll
  for (int j = 0; j < 8; j++){
    w0[j]     = waA[q * 8 + j];
    w0[8 + j] = waA[32 + q * 8 + j];
    w1[j]     = waA[64 + q * 8 + j];
    w1[8 + j] = waA[96 + q * 8 + j];
  }
  float ba0 = ba[0], ba1 = ba[1];
  long n0 = (long)bid * 128 + w * 32;
  for (int rb = 0; rb < 2; rb++, n0 += 16){
    const short8* xr = (const short8*)(x + (n0 + m) * 64);
    short8 A0 = xr[q];
    short8 A1 = xr[q + 4];
    f32x4 acc[4];
#pragma unroll
    for (int t = 0; t < 4; t++){
      acc[t] = (f32x4){bs[t], bs[t], bs[t], bs[t]};
      acc[t] = __builtin_amdgcn_mfma_f32_16x16x32_bf16(A0, Bf[t][0], acc[t], 0, 0, 0);
      acc[t] = __builtin_amdgcn_mfma_f32_16x16x32_bf16(A1, Bf[t][1], acc[t], 0, 0, 0);
    }
#pragma unroll
    for (int t = 0; t < 4; t++)
#pragma unroll
      for (int r = 0; r < 4; r++)
        h[(n0 + q * 4 + r) * 64 + t * 16 + m] = f2bs(acc[t][r]);
    float p0 = 0.f, p1 = 0.f;
#pragma unroll
    for (int j = 0; j < 8; j++){
      float va = bs2f(A0[j]);
      float vb = bs2f(A1[j]);
      p0 += va * w0[j] + vb * w0[8 + j];
      p1 += va * w1[j] + vb * w1[8 + j];
    }
    p0 += __shfl_xor(p0, 16, 64); p0 += __shfl_xor(p0, 32, 64);
    p1 += __shfl_xor(p1, 16, 64); p1 += __shfl_xor(p1, 32, 64);
    if (q == 0){ a0[n0 + m] = p0 + ba0; a1[n0 + m] = p1 + ba1; }
  }
}

// ---------------- edge softmax, thread per node: alpha[e] = exp(leaky(logit))/den ----------------
__global__ void k_alpha(const int* __restrict__ rowptr, const int* __restrict__ pedge,
                        const float* __restrict__ a0, const float* __restrict__ a1,
                        const float* __restrict__ rtab, int l,
                        float* __restrict__ alpha){
  int n = blockIdx.x * 256 + threadIdx.x;        // [0, 2NN)
  int side = n >= NN;
  const float* rt = rtab + (side * 2 + l) * 4;
  float rt0 = rt[0], rt1 = rt[1], rt2 = rt[2], rt3 = rt[3];
  int s0 = rowptr[n], s1 = rowptr[n + 1];
  float a1n = a1[n];
  float den = 0.f;
  for (int e = s0; e < s1; e++){
    int pe = pedge[e];
    int src = pe & 0x3FFFF;
    int et = (pe >> 18) & 3;
    float r = (et & 2) ? ((et & 1) ? rt3 : rt2) : ((et & 1) ? rt1 : rt0);
    float v = a0[src] + a1n + r;
    v = (v > 0.f) ? v : 0.2f * v;
    float wv = __expf(v);
    alpha[e] = wv;
    den += wv;
  }
  float inv = 1.f / (den + 1e-16f);
  for (int e = s0; e < s1; e++) alpha[e] *= inv;
}

// ---------------- GAT aggregation: wave per 8 dst nodes; pure gather-accumulate ----------------
__global__ __launch_bounds__(256) void k_agg(
    const int* __restrict__ rowptr, const int* __restrict__ pedge,
    const float* __restrict__ alpha, const unsigned* __restrict__ h32,
    unsigned* __restrict__ xo32){
  int lane = threadIdx.x & 63, w = threadIdx.x >> 6;
  int nb = (blockIdx.x * 4 + w) * 8;              // 8 nodes per wave
  int c = lane & 31, half = lane >> 5;
  int rp = (lane < 9) ? rowptr[nb + lane] : 0;
#pragma unroll
  for (int k = 0; k < 8; k++){
    int r0 = __shfl(rp, k, 64), r1 = __shfl(rp, k + 1, 64);
    float accx = 0.f, accy = 0.f;
    for (int j = r0; j < r1; j += 4){
      int eA = j + half, eB = j + 2 + half;
      int peA = 0, peB = 0; float alA = 0.f, alB = 0.f;
      bool okA = eA < r1, okB = eB < r1;
      if (okA){ peA = pedge[eA]; alA = alpha[eA]; }
      if (okB){ peB = pedge[eB]; alB = alpha[eB]; }
      if (okA){
        unsigned v = h32[(long)(peA & 0x3FFFF) * 32 + c];
        accx += alA * ulo2f(v);
        accy += alA * uhi2f(v);
      }
      if (okB){
        unsigned v = h32[(long)(peB & 0x3FFFF) * 32 + c];
        accx += alB * ulo2f(v);
        accy += alB * uhi2f(v);
      }
    }
    accx += __shfl_xor(accx, 32, 64);
    accy += __shfl_xor(accy, 32, 64);
    if (half == 0)
      xo32[(long)(nb + k) * 32 + c] = fpack(fmaxf(accx, 0.f), fmaxf(accy, 0.f));
  }
}

// ---------------- fused: y=x@poolW (MFMA), gate, gmp(x*gate), trans_w ----------------
__global__ __launch_bounds__(256) void k_scorepool(
    const short* __restrict__ x, const short8* __restrict__ frag,
    const float* __restrict__ qbuf, int l, const float* __restrict__ twW_all,
    const float* __restrict__ twb_all, float* __restrict__ xfm){
  __shared__ float gates[128];
  __shared__ float red[4][64];
  int b = blockIdx.x;                              // [0, 2NB)
  int side = b >= NB;
  int g = b - side * NB;
  const short8* pfrag = frag + 4 * 512;
  const float* q = qbuf + ((size_t)(side * 2 + l) * NB + g) * 64;
  const float* twW = twW_all + l * 4096;
  const float* twb = twb_all + l * 64;
  int off = (side ? 256 : 64) + l * 64;
  long base = (long)side * NN + (long)g * 128;
  int tid = threadIdx.x, lane = tid & 63, w = tid >> 6;
  int m = lane & 15, qd = lane >> 4;
  short8 Bf[4][2];
#pragma unroll
  for (int t = 0; t < 4; t++)
#pragma unroll
    for (int hh = 0; hh < 2; hh++)
      Bf[t][hh] = pfrag[(t * 2 + hh) * 64 + lane];
  float qv[4];
#pragma unroll
  for (int t = 0; t < 4; t++) qv[t] = q[t * 16 + m];
  for (int rb = 0; rb < 2; rb++){
    long n0 = base + w * 32 + rb * 16;
    const short8* xr = (const short8*)(x + (n0 + m) * 64);
    short8 A0 = xr[qd];
    short8 A1 = xr[qd + 4];
    f32x4 acc[4];
#pragma unroll
    for (int t = 0; t < 4; t++){
      acc[t] = (f32x4){0.f, 0.f, 0.f, 0.f};
      acc[t] = __builtin_amdgcn_mfma_f32_16x16x32_bf16(A0, Bf[t][0], acc[t], 0, 0, 0);
      acc[t] = __builtin_amdgcn_mfma_f32_16x16x32_bf16(A1, Bf[t][1], acc[t], 0, 0, 0);
    }
#pragma unroll
    for (int r = 0; r < 4; r++){
      float p = acc[0][r] * qv[0] + acc[1][r] * qv[1] + acc[2][r] * qv[2] + acc[3][r] * qv[3];
      p += __shfl_xor(p, 1, 64); p += __shfl_xor(p, 2, 64);
      p += __shfl_xor(p, 4, 64); p += __shfl_xor(p, 8, 64);
      if (m == 0)
        gates[w * 32 + rb * 16 + qd * 4 + r] = 1.f / (1.f + __expf(-p * 0.125f));
    }
  }
  __syncthreads();
  const unsigned* x32 = (const unsigned*)x;
  int c = lane & 31, half = lane >> 5;
  float mxx = 0.f, mxy = 0.f;
  for (int p = 0; p < 16; p++){
    int nn = w * 32 + 2 * p + half;
    unsigned v = x32[(base + nn) * 32 + c];
    float gt = gates[nn];
    mxx = fmaxf(mxx, ulo2f(v) * gt);
    mxy = fmaxf(mxy, uhi2f(v) * gt);
  }
  mxx = fmaxf(mxx, __shfl_xor(mxx, 32, 64));
  mxy = fmaxf(mxy, __shfl_xor(mxy, 32, 64));
  if (half == 0){ red[w][2 * c] = mxx; red[w][2 * c + 1] = mxy; }
  __syncthreads();
  if (tid < 64){
    float p = fmaxf(fmaxf(red[0][tid], red[1][tid]), fmaxf(red[2][tid], red[3][tid]));
    float o = twb[tid];
    red[0][tid] = p;
    __syncwarp();
    for (int d = 0; d < 64; d++) o += red[0][d] * twW[d * 64 + tid];
    xfm[g * 384 + off + tid] = fmaxf(o, 0.f);
  }
}

// ---------------- FM head: wave per graph, x in registers ----------------
__global__ __launch_bounds__(256) void k_fm(
    const float* __restrict__ xfm, const float* __restrict__ V,
    const float* __restrict__ fw, const float* __restrict__ bu,
    const float* __restrict__ bi, const float* __restrict__ b0,
    const int* __restrict__ uid, const int* __restrict__ iid,
    float* __restrict__ out){
  int lane = threadIdx.x & 63, w = threadIdx.x >> 6;
  int b = blockIdx.x * 4 + w;
  float xr[6], fwv[6];
#pragma unroll
  for (int t = 0; t < 6; t++){
    xr[t]  = xfm[b * 384 + lane + 64 * t];
    fwv[t] = fw[lane + 64 * t];
  }
  float xv[6] = {0.f, 0.f, 0.f, 0.f, 0.f, 0.f};
  float vv[6] = {0.f, 0.f, 0.f, 0.f, 0.f, 0.f};
  for (int k = 0; k < 384; k++){
    float xk = __shfl(xr[k >> 6], k & 63, 64);
    const float* Vr = V + (size_t)k * 384 + lane;
#pragma unroll
    for (int t = 0; t < 6; t++){
      float v = Vr[64 * t];
      float p = xk * v;
      xv[t] += p;
      vv[t] += p * p;
    }
  }
  float part = 0.f;
#pragma unroll
  for (int t = 0; t < 6; t++)
    part += 0.5f * (xv[t] * xv[t] - vv[t]) + xr[t] * fwv[t];
  part = wsum(part);
  if (lane == 0)
    out[b] = part + bu[uid[b]] + bi[iid[b]] + b0[0];
}

extern "C" void kernel_launch(void* const* d_in, const int* in_sizes, int n_in,
                              void* d_out, int out_size, void* d_ws, size_t ws_size,
                              hipStream_t stream) {
  const int* uid      = (const int*)d_in[0];
  const int* iid      = (const int*)d_in[1];
  const int* u_nodes  = (const int*)d_in[2];
  const int* i_nodes  = (const int*)d_in[3];
  const int* u_ei     = (const int*)d_in[4];
  const int* i_ei     = (const int*)d_in[5];
  const int* u_et     = (const int*)d_in[6];
  const int* i_et     = (const int*)d_in[7];
  const float* user_emb = (const float*)d_in[10];
  const float* item_emb = (const float*)d_in[11];
  const float* word_emb = (const float*)d_in[12];
  const float* trans_u_W = (const float*)d_in[13];
  const float* trans_u_b = (const float*)d_in[14];
  const float* trans_i_W = (const float*)d_in[15];
  const float* trans_i_b = (const float*)d_in[16];
  const float* trans_w_W = (const float*)d_in[17];
  const float* trans_w_b = (const float*)d_in[18];
  const float* inter_u_W = (const float*)d_in[19];
  const float* inter_u_b = (const float*)d_in[20];
  const float* inter_i_W = (const float*)d_in[21];
  const float* inter_i_b = (const float*)d_in[22];
  const float* conv_u_W  = (const float*)d_in[23];
  const float* conv_u_b  = (const float*)d_in[24];
  const float* conv_u_att= (const float*)d_in[25];
  const float* conv_u_rel= (const float*)d_in[26];
  const float* conv_i_W  = (const float*)d_in[27];
  const float* conv_i_b  = (const float*)d_in[28];
  const float* conv_i_att= (const float*)d_in[29];
  const float* conv_i_rel= (const float*)d_in[30];
  const float* pool_W    = (const float*)d_in[31];
  const float* fm_w      = (const float*)d_in[32];
  const float* fm_V      = (const float*)d_in[33];
  const float* fm_bias_u = (const float*)d_in[34];
  const float* fm_bias_i = (const float*)d_in[35];
  const float* fm_bias   = (const float*)d_in[36];
  float* out = (float*)d_out;

  // workspace carve-up (all chunks multiples of 16 B)
  char* w = (char*)d_ws;
  short* X0   = (short*)w;          w += (size_t)2 * NN * 64 * 2;   // 32 MB
  short* X1   = (short*)w;          w += (size_t)2 * NN * 64 * 2;   // 32 MB
  short* H    = (short*)w;          w += (size_t)2 * NN * 64 * 2;   // 32 MB
  int* pedge  = (int*)w;            w += (size_t)2 * NE * 4;        // 4 MB
  float* alpha= (float*)w;          w += (size_t)2 * NE * 4;        // 4 MB
  float* a0   = (float*)w;          w += (size_t)2 * NN * 4;
  float* a1   = (float*)w;          w += (size_t)2 * NN * 4;
  int* rowptr = (int*)w;            w += (size_t)(2 * NN + 256) * 4;
  int* cursor = (int*)w;            w += (size_t)2 * NN * 4;
  int* cnt    = (int*)w;            w += (size_t)2 * NN * 4;
  int* bsum   = (int*)w;            w += 1024 * 4;
  short8* frag = (short8*)w;        w += (size_t)5 * 512 * 16;      // 5 matrices
  float* waA  = (float*)w;          w += 2 * 2 * 2 * 64 * 4;
  float* ba   = (float*)w;          w += 64;
  float* rtab = (float*)w;          w += 64;
  float* qbuf = (float*)w;          w += (size_t)4 * NB * 64 * 4;
  float* xfm  = (float*)w;          w += (size_t)NB * 384 * 4;

  k_wprep  <<<12, 256, 0, stream>>>(conv_u_W, conv_i_W, pool_W, conv_u_b, conv_i_b,
                                    conv_u_att, conv_i_att, conv_u_rel, conv_i_rel,
                                    frag, waA, ba, rtab);
  k_zero   <<<2 * NN / 256, 256, 0, stream>>>(cnt);
  k_hist   <<<2 * NE / 256, 256, 0, stream>>>(u_ei, i_ei, cnt);
  k_scan1  <<<2 * NN / 256, 256, 0, stream>>>(cnt, rowptr, bsum);
  k_scan2  <<<1, 1024, 0, stream>>>(bsum);
  k_scan3  <<<2 * NN / 256, 256, 0, stream>>>(rowptr, bsum, cursor);
  k_scatter<<<2 * NE / 256, 256, 0, stream>>>(u_ei, i_ei, u_et, i_et, cursor, pedge);
  k_gather <<<2 * NN * 32 / 256, 256, 0, stream>>>(u_nodes, i_nodes, word_emb,
                                                   (unsigned*)X0);
  k_prep   <<<2 * NB / 4, 256, 0, stream>>>(uid, iid, user_emb, item_emb,
                                            inter_u_W, inter_u_b, inter_i_W, inter_i_b,
                                            trans_u_W, trans_u_b, trans_i_W, trans_i_b,
                                            xfm, qbuf);

  short* A = X0; short* Bv = X1;
  for (int l = 0; l < 2; ++l){
    k_gemm_h<<<2 * NN / 128, 256, 0, stream>>>(A, frag, conv_u_b, conv_i_b, l,
                                               waA, ba, H, a0, a1);
    k_alpha <<<2 * NN / 256, 256, 0, stream>>>(rowptr, pedge, a0, a1, rtab, l, alpha);
    k_agg   <<<2 * NN / 32, 256, 0, stream>>>(rowptr, pedge, alpha,
                                              (const unsigned*)H, (unsigned*)Bv);
    k_scorepool<<<2 * NB, 256, 0, stream>>>(Bv, frag, qbuf, l, trans_w_W, trans_w_b, xfm);
    short* t = A; A = Bv; Bv = t;
  }

  k_fm<<<NB / 4, 256, 0, stream>>>(xfm, fm_V, fm_w, fm_bias_u, fm_bias_i, fm_bias,
                                   uid, iid, out);
}

// Round 6
// 501.748 us; speedup vs baseline: 1.1319x; 1.1319x over previous
//
#include <hip/hip_runtime.h>
#include <hip/hip_bf16.h>

#define NN 131072   // nodes per side
#define NE 524288   // edges per side
#define NB 1024     // batch (graphs per side)

typedef __attribute__((ext_vector_type(8))) short short8;   // 8 bf16
typedef __attribute__((ext_vector_type(4))) float f32x4;

__device__ __forceinline__ float wsum(float v){
#pragma unroll
  for (int o = 32; o > 0; o >>= 1) v += __shfl_xor(v, o, 64);
  return v;
}
__device__ __forceinline__ short f2bs(float f){
  __hip_bfloat16 t = __float2bfloat16(f);
  union { __hip_bfloat16 b; short s; } u; u.b = t; return u.s;
}
__device__ __forceinline__ float bs2f(short s){
  return __uint_as_float(((unsigned)(unsigned short)s) << 16);
}
__device__ __forceinline__ float ulo2f(unsigned v){ return __uint_as_float(v << 16); }
__device__ __forceinline__ float uhi2f(unsigned v){ return __uint_as_float(v & 0xFFFF0000u); }
__device__ __forceinline__ unsigned fpack(float x, float y){
  return (unsigned)(unsigned short)f2bs(x) | ((unsigned)(unsigned short)f2bs(y) << 16);
}

// ---------------- CSR build (both sides; global node = side*NN + n) ----------------
__global__ void k_zero(int* __restrict__ p){
  p[blockIdx.x * 256 + threadIdx.x] = 0;
}

__global__ void k_hist(const int* __restrict__ u_ei, const int* __restrict__ i_ei,
                       int* __restrict__ cnt){
  int ee = blockIdx.x * 256 + threadIdx.x;       // [0, 2NE)
  int side = ee >= NE;
  int e = ee - side * NE;
  const int* ei = side ? i_ei : u_ei;
  atomicAdd(&cnt[ei[NE + e] + side * NN], 1);
}

__global__ void k_scan1(const int* __restrict__ cnt, int* __restrict__ rowptr,
                        int* __restrict__ bsum){
  __shared__ int sh[256];
  int i = blockIdx.x * 256 + threadIdx.x;
  int v = cnt[i];
  sh[threadIdx.x] = v; __syncthreads();
  for (int off = 1; off < 256; off <<= 1){
    int t = (threadIdx.x >= off) ? sh[threadIdx.x - off] : 0;
    __syncthreads();
    sh[threadIdx.x] += t;
    __syncthreads();
  }
  int incl = sh[threadIdx.x];
  rowptr[i] = incl - v;
  if (threadIdx.x == 255) bsum[blockIdx.x] = incl;
}

__global__ void k_scan2(int* __restrict__ bsum){
  __shared__ int sh[1024];
  int v = bsum[threadIdx.x];
  sh[threadIdx.x] = v; __syncthreads();
  for (int off = 1; off < 1024; off <<= 1){
    int t = (threadIdx.x >= off) ? sh[threadIdx.x - off] : 0;
    __syncthreads();
    sh[threadIdx.x] += t;
    __syncthreads();
  }
  bsum[threadIdx.x] = sh[threadIdx.x] - v;  // exclusive
}

__global__ void k_scan3(int* __restrict__ rowptr, const int* __restrict__ bsum,
                        int* __restrict__ cursor){
  int i = blockIdx.x * 256 + threadIdx.x;
  int v = rowptr[i] + bsum[blockIdx.x];
  rowptr[i] = v;
  cursor[i] = v;
  if (i == 0) rowptr[2 * NN] = 2 * NE;
}

__global__ void k_scatter(const int* __restrict__ u_ei, const int* __restrict__ i_ei,
                          const int* __restrict__ u_et, const int* __restrict__ i_et,
                          int* __restrict__ cursor, int* __restrict__ pedge){
  int ee = blockIdx.x * 256 + threadIdx.x;
  int side = ee >= NE;
  int e = ee - side * NE;
  const int* ei = side ? i_ei : u_ei;
  const int* et = side ? i_et : u_et;
  int src = ei[e] + side * NN;
  int dst = ei[NE + e] + side * NN;
  int p = atomicAdd(&cursor[dst], 1);
  pedge[p] = src | (et[e] << 18);
}

// ---------------- word_emb fp32 -> bf16 table (coalesced, once) ----------------
__global__ void k_wconv(const float* __restrict__ wemb, unsigned* __restrict__ wtab,
                        int n32){
  int id = blockIdx.x * 256 + threadIdx.x;
  if (id >= n32) return;
  const float2* src = (const float2*)wemb;
  float2 v = src[id];
  wtab[id] = fpack(v.x, v.y);
}

// ---------------- weight prep: MFMA B-frags for 5 matrices + waA/ba/rtab both sides ----------------
__global__ void k_wprep(const float* __restrict__ cuW, const float* __restrict__ ciW,
                        const float* __restrict__ pW,
                        const float* __restrict__ cub, const float* __restrict__ cib,
                        const float* __restrict__ uatt, const float* __restrict__ iatt,
                        const float* __restrict__ urel, const float* __restrict__ irel,
                        short8* __restrict__ frag, float* __restrict__ waA,
                        float* __restrict__ ba, float* __restrict__ rtab){
  int blk = blockIdx.x, tid = threadIdx.x;
  if (blk < 10){
    int mat = blk >> 1;
    const float* W = mat < 2 ? cuW + mat * 4096 : (mat < 4 ? ciW + (mat - 2) * 4096 : pW);
    int g = (blk & 1) * 256 + tid;     // [0,512)
    int lane = g & 63, rest = g >> 6;
    int hh = rest & 1, t = rest >> 1;
    int m = lane & 15, q = lane >> 4;
    short8 v;
#pragma unroll
    for (int j = 0; j < 8; j++)
      v[j] = f2bs(W[(hh * 32 + q * 8 + j) * 64 + (t * 16 + m)]);
    frag[mat * 512 + g] = v;
  } else {
    int side = blk - 10;
    const float* W    = side ? ciW : cuW;
    const float* bias = side ? cib : cub;
    const float* att  = side ? iatt : uatt;
    const float* rel  = side ? irel : urel;
    int l = tid >> 7, a = (tid >> 6) & 1, kk = tid & 63;
    float s = 0.f;
    for (int c = 0; c < 64; c++) s += W[l * 4096 + kk * 64 + c] * att[l * 192 + a * 64 + c];
    waA[((side * 2 + l) * 2 + a) * 64 + kk] = s;
    if (tid < 4){
      int l2 = tid >> 1, a2 = tid & 1;
      float sb = 0.f;
      for (int c = 0; c < 64; c++) sb += bias[l2 * 64 + c] * att[l2 * 192 + a2 * 64 + c];
      ba[(side * 2 + l2) * 2 + a2] = sb;
    }
    if (tid >= 4 && tid < 12){
      int id = tid - 4, l2 = id >> 2, tt = id & 3;
      float sr = 0.f;
      for (int c = 0; c < 64; c++) sr += rel[l2 * 256 + tt * 64 + c] * att[l2 * 192 + 128 + c];
      rtab[(side * 2 + l2) * 4 + tt] = sr;
    }
  }
}

// ---------------- per-interaction prep: rep (inter) + queries (both sides) ----------------
__global__ void k_prep(const int* __restrict__ uid, const int* __restrict__ iid,
                       const float* __restrict__ uemb, const float* __restrict__ iemb,
                       const float* __restrict__ uiW, const float* __restrict__ uib,
                       const float* __restrict__ iiW, const float* __restrict__ iib,
                       const float* __restrict__ utW, const float* __restrict__ utb,
                       const float* __restrict__ itW, const float* __restrict__ itb,
                       float* __restrict__ xfm, float* __restrict__ q){
  int lane = threadIdx.x & 63, w = threadIdx.x >> 6;
  int b = blockIdx.x * 4 + w;                     // [0, 2NB)
  int side = b >= NB;
  int lb = b - side * NB;
  const int* ids = side ? iid : uid;
  const float* emb = side ? iemb : uemb;
  const float* interW = side ? iiW : uiW;
  const float* interB = side ? iib : uib;
  const float* transW = side ? itW : utW;
  const float* transB = side ? itb : utb;
  int repOff = side ? 192 : 0;
  float xe = emb[(long)ids[lb] * 64 + lane];
  float o = interB[lane];
#pragma unroll
  for (int k = 0; k < 64; k++) o += __shfl(xe, k, 64) * interW[k * 64 + lane];
  xfm[lb * 384 + repOff + lane] = fmaxf(o, 0.f);
  for (int l = 0; l < 2; l++){
    float t = transB[l * 64 + lane];
#pragma unroll
    for (int k = 0; k < 64; k++) t += __shfl(xe, k, 64) * transW[l * 4096 + k * 64 + lane];
    q[((size_t)(side * 2 + l) * NB + lb) * 64 + lane] = fmaxf(t, 0.f);
  }
}

// ---------------- MFMA: h = x @ W + b (bf16 out) ; fused a0/a1 = x.waA + ba ----------------
// l==0: A-rows gathered from bf16 word table via node indices; l==1: coalesced from x.
__global__ __launch_bounds__(256) void k_gemm_h(
    const short* __restrict__ x, const short* __restrict__ wtab,
    const int* __restrict__ u_nodes, const int* __restrict__ i_nodes,
    const short8* __restrict__ cfrag,
    const float* __restrict__ cub, const float* __restrict__ cib, int l,
    const float* __restrict__ waA_all, const float* __restrict__ ba_all,
    short* __restrict__ h, float* __restrict__ a0, float* __restrict__ a1){
  int bid = blockIdx.x;
  int side = bid >= (NN / 128);
  const short8* wfrag = cfrag + (side * 2 + l) * 512;
  const float* bias = (side ? cib : cub) + l * 64;
  const float* waA = waA_all + (side * 2 + l) * 128;
  const float* ba = ba_all + (side * 2 + l) * 2;
  const int* nodes = side ? i_nodes : u_nodes;
  int lane = threadIdx.x & 63, w = threadIdx.x >> 6;
  int m = lane & 15, q = lane >> 4;
  short8 Bf[4][2];
#pragma unroll
  for (int t = 0; t < 4; t++)
#pragma unroll
    for (int hh = 0; hh < 2; hh++)
      Bf[t][hh] = wfrag[(t * 2 + hh) * 64 + lane];
  float bs[4];
#pragma unroll
  for (int t = 0; t < 4; t++) bs[t] = bias[t * 16 + m];
  float w0[16], w1[16];
#pragma unroll
  for (int j = 0; j < 8; j++){
    w0[j]     = waA[q * 8 + j];
    w0[8 + j] = waA[32 + q * 8 + j];
    w1[j]     = waA[64 + q * 8 + j];
    w1[8 + j] = waA[96 + q * 8 + j];
  }
  float ba0 = ba[0], ba1 = ba[1];
  long n0 = (long)bid * 128 + w * 32;
  for (int rb = 0; rb < 2; rb++, n0 += 16){
    const short8* xr;
    if (l == 0){
      long local = n0 + m - (long)side * NN;
      xr = (const short8*)(wtab + (long)nodes[local] * 64);
    } else {
      xr = (const short8*)(x + (n0 + m) * 64);
    }
    short8 A0 = xr[q];
    short8 A1 = xr[q + 4];
    f32x4 acc[4];
#pragma unroll
    for (int t = 0; t < 4; t++){
      acc[t] = (f32x4){bs[t], bs[t], bs[t], bs[t]};
      acc[t] = __builtin_amdgcn_mfma_f32_16x16x32_bf16(A0, Bf[t][0], acc[t], 0, 0, 0);
      acc[t] = __builtin_amdgcn_mfma_f32_16x16x32_bf16(A1, Bf[t][1], acc[t], 0, 0, 0);
    }
#pragma unroll
    for (int t = 0; t < 4; t++)
#pragma unroll
      for (int r = 0; r < 4; r++)
        h[(n0 + q * 4 + r) * 64 + t * 16 + m] = f2bs(acc[t][r]);
    float p0 = 0.f, p1 = 0.f;
#pragma unroll
    for (int j = 0; j < 8; j++){
      float va = bs2f(A0[j]);
      float vb = bs2f(A1[j]);
      p0 += va * w0[j] + vb * w0[8 + j];
      p1 += va * w1[j] + vb * w1[8 + j];
    }
    p0 += __shfl_xor(p0, 16, 64); p0 += __shfl_xor(p0, 32, 64);
    p1 += __shfl_xor(p1, 16, 64); p1 += __shfl_xor(p1, 32, 64);
    if (q == 0){ a0[n0 + m] = p0 + ba0; a1[n0 + m] = p1 + ba1; }
  }
}

// ---------------- edge weights (one pass): alpha[e] = exp(leaky(logit)), inv_den[n] ----------------
__global__ void k_alpha(const int* __restrict__ rowptr, const int* __restrict__ pedge,
                        const float* __restrict__ a0, const float* __restrict__ a1,
                        const float* __restrict__ rtab, int l,
                        float* __restrict__ alpha, float* __restrict__ inv_den){
  int n = blockIdx.x * 256 + threadIdx.x;        // [0, 2NN)
  int side = n >= NN;
  const float* rt = rtab + (side * 2 + l) * 4;
  float rt0 = rt[0], rt1 = rt[1], rt2 = rt[2], rt3 = rt[3];
  int s0 = rowptr[n], s1 = rowptr[n + 1];
  float a1n = a1[n];
  float den = 0.f;
  for (int e = s0; e < s1; e++){
    int pe = pedge[e];
    int src = pe & 0x3FFFF;
    int et = (pe >> 18) & 3;
    float r = (et & 2) ? ((et & 1) ? rt3 : rt2) : ((et & 1) ? rt1 : rt0);
    float v = a0[src] + a1n + r;
    v = (v > 0.f) ? v : 0.2f * v;
    float wv = __expf(v);
    alpha[e] = wv;
    den += wv;
  }
  inv_den[n] = 1.f / (den + 1e-16f);
}

// ---------------- GAT aggregation: wave per 8 dst nodes; quarter-wave per edge ----------------
__global__ __launch_bounds__(256) void k_agg(
    const int* __restrict__ rowptr, const int* __restrict__ pedge,
    const float* __restrict__ alpha, const float* __restrict__ inv_den,
    const unsigned* __restrict__ h32, unsigned* __restrict__ xo32){
  int lane = threadIdx.x & 63, w = threadIdx.x >> 6;
  int nb = (blockIdx.x * 4 + w) * 8;              // 8 nodes per wave
  int q = lane >> 4, cl = lane & 15;              // quarter, uint2 index within 128B row
  int rp = (lane < 9) ? rowptr[nb + lane] : 0;
  float idn = (lane < 8) ? inv_den[nb + lane] : 0.f;
  int rp0 = __shfl(rp, 0, 64);
  int rp8 = __shfl(rp, 8, 64);
  int tot = min(rp8 - rp0, 64);
  // coalesced preload of the wave's edge window
  int psrc = 0; float pal = 0.f;
  if (lane < tot){
    psrc = pedge[rp0 + lane] & 0x3FFFF;
    pal  = alpha[rp0 + lane];
  }
  const uint2* h2 = (const uint2*)h32;
#pragma unroll
  for (int k = 0; k < 8; k++){
    int r0 = __shfl(rp, k, 64), r1 = __shfl(rp, k + 1, 64);
    float ax0 = 0.f, ay0 = 0.f, ax1 = 0.f, ay1 = 0.f;
    for (int j = r0; j < r1; j += 4){
      int e = j + q;
      bool ok = e < r1;
      int idx = e - rp0;
      int idxc = min(idx, 63);
      int s = __shfl(psrc, idxc, 64);
      float al = __shfl(pal, idxc, 64);
      if (idx >= 64){                 // rare spill past preload window
        int pe = pedge[e];
        s = pe & 0x3FFFF;
        al = alpha[e];
      }
      if (ok){
        uint2 v = h2[(long)s * 16 + cl];
        ax0 += al * ulo2f(v.x); ay0 += al * uhi2f(v.x);
        ax1 += al * ulo2f(v.y); ay1 += al * uhi2f(v.y);
      }
    }
    ax0 += __shfl_xor(ax0, 16, 64); ax0 += __shfl_xor(ax0, 32, 64);
    ay0 += __shfl_xor(ay0, 16, 64); ay0 += __shfl_xor(ay0, 32, 64);
    ax1 += __shfl_xor(ax1, 16, 64); ax1 += __shfl_xor(ax1, 32, 64);
    ay1 += __shfl_xor(ay1, 16, 64); ay1 += __shfl_xor(ay1, 32, 64);
    float dk = __shfl(idn, k, 64);
    if (q == 0){
      uint2 o;
      o.x = fpack(fmaxf(ax0 * dk, 0.f), fmaxf(ay0 * dk, 0.f));
      o.y = fpack(fmaxf(ax1 * dk, 0.f), fmaxf(ay1 * dk, 0.f));
      ((uint2*)xo32)[(long)(nb + k) * 16 + cl] = o;
    }
  }
}

// ---------------- fused: y=x@poolW (MFMA), gate, gmp(x*gate), trans_w ----------------
__global__ __launch_bounds__(256) void k_scorepool(
    const short* __restrict__ x, const short8* __restrict__ frag,
    const float* __restrict__ qbuf, int l, const float* __restrict__ twW_all,
    const float* __restrict__ twb_all, float* __restrict__ xfm){
  __shared__ float gates[128];
  __shared__ float red[4][64];
  int b = blockIdx.x;                              // [0, 2NB)
  int side = b >= NB;
  int g = b - side * NB;
  const short8* pfrag = frag + 4 * 512;
  const float* q = qbuf + ((size_t)(side * 2 + l) * NB + g) * 64;
  const float* twW = twW_all + l * 4096;
  const float* twb = twb_all + l * 64;
  int off = (side ? 256 : 64) + l * 64;
  long base = (long)side * NN + (long)g * 128;
  int tid = threadIdx.x, lane = tid & 63, w = tid >> 6;
  int m = lane & 15, qd = lane >> 4;
  short8 Bf[4][2];
#pragma unroll
  for (int t = 0; t < 4; t++)
#pragma unroll
    for (int hh = 0; hh < 2; hh++)
      Bf[t][hh] = pfrag[(t * 2 + hh) * 64 + lane];
  float qv[4];
#pragma unroll
  for (int t = 0; t < 4; t++) qv[t] = q[t * 16 + m];
  for (int rb = 0; rb < 2; rb++){
    long n0 = base + w * 32 + rb * 16;
    const short8* xr = (const short8*)(x + (n0 + m) * 64);
    short8 A0 = xr[qd];
    short8 A1 = xr[qd + 4];
    f32x4 acc[4];
#pragma unroll
    for (int t = 0; t < 4; t++){
      acc[t] = (f32x4){0.f, 0.f, 0.f, 0.f};
      acc[t] = __builtin_amdgcn_mfma_f32_16x16x32_bf16(A0, Bf[t][0], acc[t], 0, 0, 0);
      acc[t] = __builtin_amdgcn_mfma_f32_16x16x32_bf16(A1, Bf[t][1], acc[t], 0, 0, 0);
    }
#pragma unroll
    for (int r = 0; r < 4; r++){
      float p = acc[0][r] * qv[0] + acc[1][r] * qv[1] + acc[2][r] * qv[2] + acc[3][r] * qv[3];
      p += __shfl_xor(p, 1, 64); p += __shfl_xor(p, 2, 64);
      p += __shfl_xor(p, 4, 64); p += __shfl_xor(p, 8, 64);
      if (m == 0)
        gates[w * 32 + rb * 16 + qd * 4 + r] = 1.f / (1.f + __expf(-p * 0.125f));
    }
  }
  __syncthreads();
  const unsigned* x32 = (const unsigned*)x;
  int c = lane & 31, half = lane >> 5;
  float mxx = 0.f, mxy = 0.f;
  for (int p = 0; p < 16; p++){
    int nn = w * 32 + 2 * p + half;
    unsigned v = x32[(base + nn) * 32 + c];
    float gt = gates[nn];
    mxx = fmaxf(mxx, ulo2f(v) * gt);
    mxy = fmaxf(mxy, uhi2f(v) * gt);
  }
  mxx = fmaxf(mxx, __shfl_xor(mxx, 32, 64));
  mxy = fmaxf(mxy, __shfl_xor(mxy, 32, 64));
  if (half == 0){ red[w][2 * c] = mxx; red[w][2 * c + 1] = mxy; }
  __syncthreads();
  if (tid < 64){
    float p = fmaxf(fmaxf(red[0][tid], red[1][tid]), fmaxf(red[2][tid], red[3][tid]));
    float o = twb[tid];
    red[0][tid] = p;
    __syncwarp();
    for (int d = 0; d < 64; d++) o += red[0][d] * twW[d * 64 + tid];
    xfm[g * 384 + off + tid] = fmaxf(o, 0.f);
  }
}

// ---------------- FM head: wave per graph, x in registers ----------------
__global__ __launch_bounds__(256) void k_fm(
    const float* __restrict__ xfm, const float* __restrict__ V,
    const float* __restrict__ fw, const float* __restrict__ bu,
    const float* __restrict__ bi, const float* __restrict__ b0,
    const int* __restrict__ uid, const int* __restrict__ iid,
    float* __restrict__ out){
  int lane = threadIdx.x & 63, w = threadIdx.x >> 6;
  int b = blockIdx.x * 4 + w;
  float xr[6], fwv[6];
#pragma unroll
  for (int t = 0; t < 6; t++){
    xr[t]  = xfm[b * 384 + lane + 64 * t];
    fwv[t] = fw[lane + 64 * t];
  }
  float xv[6] = {0.f, 0.f, 0.f, 0.f, 0.f, 0.f};
  float vv[6] = {0.f, 0.f, 0.f, 0.f, 0.f, 0.f};
  for (int k = 0; k < 384; k++){
    float xk = __shfl(xr[k >> 6], k & 63, 64);
    const float* Vr = V + (size_t)k * 384 + lane;
#pragma unroll
    for (int t = 0; t < 6; t++){
      float v = Vr[64 * t];
      float p = xk * v;
      xv[t] += p;
      vv[t] += p * p;
    }
  }
  float part = 0.f;
#pragma unroll
  for (int t = 0; t < 6; t++)
    part += 0.5f * (xv[t] * xv[t] - vv[t]) + xr[t] * fwv[t];
  part = wsum(part);
  if (lane == 0)
    out[b] = part + bu[uid[b]] + bi[iid[b]] + b0[0];
}

extern "C" void kernel_launch(void* const* d_in, const int* in_sizes, int n_in,
                              void* d_out, int out_size, void* d_ws, size_t ws_size,
                              hipStream_t stream) {
  const int* uid      = (const int*)d_in[0];
  const int* iid      = (const int*)d_in[1];
  const int* u_nodes  = (const int*)d_in[2];
  const int* i_nodes  = (const int*)d_in[3];
  const int* u_ei     = (const int*)d_in[4];
  const int* i_ei     = (const int*)d_in[5];
  const int* u_et     = (const int*)d_in[6];
  const int* i_et     = (const int*)d_in[7];
  const float* user_emb = (const float*)d_in[10];
  const float* item_emb = (const float*)d_in[11];
  const float* word_emb = (const float*)d_in[12];
  const float* trans_u_W = (const float*)d_in[13];
  const float* trans_u_b = (const float*)d_in[14];
  const float* trans_i_W = (const float*)d_in[15];
  const float* trans_i_b = (const float*)d_in[16];
  const float* trans_w_W = (const float*)d_in[17];
  const float* trans_w_b = (const float*)d_in[18];
  const float* inter_u_W = (const float*)d_in[19];
  const float* inter_u_b = (const float*)d_in[20];
  const float* inter_i_W = (const float*)d_in[21];
  const float* inter_i_b = (const float*)d_in[22];
  const float* conv_u_W  = (const float*)d_in[23];
  const float* conv_u_b  = (const float*)d_in[24];
  const float* conv_u_att= (const float*)d_in[25];
  const float* conv_u_rel= (const float*)d_in[26];
  const float* conv_i_W  = (const float*)d_in[27];
  const float* conv_i_b  = (const float*)d_in[28];
  const float* conv_i_att= (const float*)d_in[29];
  const float* conv_i_rel= (const float*)d_in[30];
  const float* pool_W    = (const float*)d_in[31];
  const float* fm_w      = (const float*)d_in[32];
  const float* fm_V      = (const float*)d_in[33];
  const float* fm_bias_u = (const float*)d_in[34];
  const float* fm_bias_i = (const float*)d_in[35];
  const float* fm_bias   = (const float*)d_in[36];
  float* out = (float*)d_out;
  int nwords32 = in_sizes[12] / 2;   // fp32 elements / 2 = packed uints

  // workspace carve-up (all chunks multiples of 16 B)
  char* w = (char*)d_ws;
  short* X0   = (short*)w;          w += (size_t)2 * NN * 64 * 2;   // 32 MB
  short* X1   = (short*)w;          w += (size_t)2 * NN * 64 * 2;   // 32 MB
  short* H    = (short*)w;          w += (size_t)2 * NN * 64 * 2;   // 32 MB
  short* wtab = (short*)w;          w += (size_t)in_sizes[12] * 2;  // bf16 word table
  int* pedge  = (int*)w;            w += (size_t)2 * NE * 4;        // 4 MB
  float* alpha= (float*)w;          w += (size_t)2 * NE * 4;        // 4 MB
  float* a0   = (float*)w;          w += (size_t)2 * NN * 4;
  float* a1   = (float*)w;          w += (size_t)2 * NN * 4;
  float* invd = (float*)w;          w += (size_t)2 * NN * 4;
  int* rowptr = (int*)w;            w += (size_t)(2 * NN + 256) * 4;
  int* cursor = (int*)w;            w += (size_t)2 * NN * 4;
  int* cnt    = (int*)w;            w += (size_t)2 * NN * 4;
  int* bsum   = (int*)w;            w += 1024 * 4;
  short8* frag = (short8*)w;        w += (size_t)5 * 512 * 16;      // 5 matrices
  float* waA  = (float*)w;          w += 2 * 2 * 2 * 64 * 4;
  float* ba   = (float*)w;          w += 64;
  float* rtab = (float*)w;          w += 64;
  float* qbuf = (float*)w;          w += (size_t)4 * NB * 64 * 4;
  float* xfm  = (float*)w;          w += (size_t)NB * 384 * 4;

  k_wprep  <<<12, 256, 0, stream>>>(conv_u_W, conv_i_W, pool_W, conv_u_b, conv_i_b,
                                    conv_u_att, conv_i_att, conv_u_rel, conv_i_rel,
                                    frag, waA, ba, rtab);
  k_wconv  <<<(nwords32 + 255) / 256, 256, 0, stream>>>(word_emb, (unsigned*)wtab,
                                                        nwords32);
  k_zero   <<<2 * NN / 256, 256, 0, stream>>>(cnt);
  k_hist   <<<2 * NE / 256, 256, 0, stream>>>(u_ei, i_ei, cnt);
  k_scan1  <<<2 * NN / 256, 256, 0, stream>>>(cnt, rowptr, bsum);
  k_scan2  <<<1, 1024, 0, stream>>>(bsum);
  k_scan3  <<<2 * NN / 256, 256, 0, stream>>>(rowptr, bsum, cursor);
  k_scatter<<<2 * NE / 256, 256, 0, stream>>>(u_ei, i_ei, u_et, i_et, cursor, pedge);
  k_prep   <<<2 * NB / 4, 256, 0, stream>>>(uid, iid, user_emb, item_emb,
                                            inter_u_W, inter_u_b, inter_i_W, inter_i_b,
                                            trans_u_W, trans_u_b, trans_i_W, trans_i_b,
                                            xfm, qbuf);

  short* Xin = X0;   // l=0 ignores Xin (reads wtab)
  for (int l = 0; l < 2; ++l){
    short* Xout = l == 0 ? X0 : X1;
    k_gemm_h<<<2 * NN / 128, 256, 0, stream>>>(Xin, wtab, u_nodes, i_nodes, frag,
                                               conv_u_b, conv_i_b, l,
                                               waA, ba, H, a0, a1);
    k_alpha <<<2 * NN / 256, 256, 0, stream>>>(rowptr, pedge, a0, a1, rtab, l,
                                               alpha, invd);
    k_agg   <<<2 * NN / 32, 256, 0, stream>>>(rowptr, pedge, alpha, invd,
                                              (const unsigned*)H, (unsigned*)Xout);
    k_scorepool<<<2 * NB, 256, 0, stream>>>(Xout, frag, qbuf, l,
                                            trans_w_W, trans_w_b, xfm);
    Xin = Xout;
  }

  k_fm<<<NB / 4, 256, 0, stream>>>(xfm, fm_V, fm_w, fm_bias_u, fm_bias_i, fm_bias,
                                   uid, iid, out);
}

// Round 7
// 482.530 us; speedup vs baseline: 1.1770x; 1.0398x over previous
//
#include <hip/hip_runtime.h>
#include <hip/hip_bf16.h>

#define NN 131072   // nodes per side
#define NE 524288   // edges per side
#define NB 1024     // batch (graphs per side)

typedef __attribute__((ext_vector_type(8))) short short8;   // 8 bf16
typedef __attribute__((ext_vector_type(4))) float f32x4;

__device__ __forceinline__ float wsum(float v){
#pragma unroll
  for (int o = 32; o > 0; o >>= 1) v += __shfl_xor(v, o, 64);
  return v;
}
__device__ __forceinline__ short f2bs(float f){
  __hip_bfloat16 t = __float2bfloat16(f);
  union { __hip_bfloat16 b; short s; } u; u.b = t; return u.s;
}
__device__ __forceinline__ float bs2f(short s){
  return __uint_as_float(((unsigned)(unsigned short)s) << 16);
}
__device__ __forceinline__ float ulo2f(unsigned v){ return __uint_as_float(v << 16); }
__device__ __forceinline__ float uhi2f(unsigned v){ return __uint_as_float(v & 0xFFFF0000u); }
__device__ __forceinline__ unsigned fpack(float x, float y){
  return (unsigned)(unsigned short)f2bs(x) | ((unsigned)(unsigned short)f2bs(y) << 16);
}

// ---------------- CSR build (both sides; global node = side*NN + n) ----------------
__global__ void k_zero(int* __restrict__ p){
  p[blockIdx.x * 256 + threadIdx.x] = 0;
}

// XCD-partitioned histogram: block b only counts dsts in partition (b&7).
// Round-robin block->XCD dispatch keeps each cnt line owned by one XCD L2.
__global__ void k_hist(const int* __restrict__ u_ei, const int* __restrict__ i_ei,
                       int* __restrict__ cnt){
  int b = blockIdx.x;
  int x = b & 7;
  int ee = (b >> 3) * 256 + threadIdx.x;         // [0, 2NE)
  int side = ee >= NE;
  int e = ee - side * NE;
  const int* ei = side ? i_ei : u_ei;
  int dst = ei[NE + e] + side * NN;
  if ((dst >> 15) == x) atomicAdd(&cnt[dst], 1);
}

__global__ void k_scan1(const int* __restrict__ cnt, int* __restrict__ rowptr,
                        int* __restrict__ bsum){
  __shared__ int sh[256];
  int i = blockIdx.x * 256 + threadIdx.x;
  int v = cnt[i];
  sh[threadIdx.x] = v; __syncthreads();
  for (int off = 1; off < 256; off <<= 1){
    int t = (threadIdx.x >= off) ? sh[threadIdx.x - off] : 0;
    __syncthreads();
    sh[threadIdx.x] += t;
    __syncthreads();
  }
  int incl = sh[threadIdx.x];
  rowptr[i] = incl - v;
  if (threadIdx.x == 255) bsum[blockIdx.x] = incl;
}

__global__ void k_scan2(int* __restrict__ bsum){
  __shared__ int sh[1024];
  int v = bsum[threadIdx.x];
  sh[threadIdx.x] = v; __syncthreads();
  for (int off = 1; off < 1024; off <<= 1){
    int t = (threadIdx.x >= off) ? sh[threadIdx.x - off] : 0;
    __syncthreads();
    sh[threadIdx.x] += t;
    __syncthreads();
  }
  bsum[threadIdx.x] = sh[threadIdx.x] - v;  // exclusive
}

__global__ void k_scan3(int* __restrict__ rowptr, const int* __restrict__ bsum,
                        int* __restrict__ cursor){
  int i = blockIdx.x * 256 + threadIdx.x;
  int v = rowptr[i] + bsum[blockIdx.x];
  rowptr[i] = v;
  cursor[i] = v;
  if (i == 0) rowptr[2 * NN] = 2 * NE;
}

// XCD-partitioned scatter: only matching lanes do the atomic + store, so the
// random pedge/cursor writes for a partition come from one XCD.
__global__ void k_scatter(const int* __restrict__ u_ei, const int* __restrict__ i_ei,
                          const int* __restrict__ u_et, const int* __restrict__ i_et,
                          int* __restrict__ cursor, int* __restrict__ pedge){
  int b = blockIdx.x;
  int x = b & 7;
  int ee = (b >> 3) * 256 + threadIdx.x;
  int side = ee >= NE;
  int e = ee - side * NE;
  const int* ei = side ? i_ei : u_ei;
  int dst = ei[NE + e] + side * NN;
  if ((dst >> 15) == x){
    const int* et = side ? i_et : u_et;
    int src = ei[e] + side * NN;
    int p = atomicAdd(&cursor[dst], 1);
    pedge[p] = src | (et[e] << 18);
  }
}

// ---------------- word_emb fp32 -> bf16 table (coalesced, once) ----------------
__global__ void k_wconv(const float* __restrict__ wemb, unsigned* __restrict__ wtab,
                        int n32){
  int id = blockIdx.x * 256 + threadIdx.x;
  if (id >= n32) return;
  const float2* src = (const float2*)wemb;
  float2 v = src[id];
  wtab[id] = fpack(v.x, v.y);
}

// ---------------- weight prep: MFMA B-frags for 5 matrices + waA/ba/rtab both sides ----------------
__global__ void k_wprep(const float* __restrict__ cuW, const float* __restrict__ ciW,
                        const float* __restrict__ pW,
                        const float* __restrict__ cub, const float* __restrict__ cib,
                        const float* __restrict__ uatt, const float* __restrict__ iatt,
                        const float* __restrict__ urel, const float* __restrict__ irel,
                        short8* __restrict__ frag, float* __restrict__ waA,
                        float* __restrict__ ba, float* __restrict__ rtab){
  int blk = blockIdx.x, tid = threadIdx.x;
  if (blk < 10){
    int mat = blk >> 1;
    const float* W = mat < 2 ? cuW + mat * 4096 : (mat < 4 ? ciW + (mat - 2) * 4096 : pW);
    int g = (blk & 1) * 256 + tid;     // [0,512)
    int lane = g & 63, rest = g >> 6;
    int hh = rest & 1, t = rest >> 1;
    int m = lane & 15, q = lane >> 4;
    short8 v;
#pragma unroll
    for (int j = 0; j < 8; j++)
      v[j] = f2bs(W[(hh * 32 + q * 8 + j) * 64 + (t * 16 + m)]);
    frag[mat * 512 + g] = v;
  } else {
    int side = blk - 10;
    const float* W    = side ? ciW : cuW;
    const float* bias = side ? cib : cub;
    const float* att  = side ? iatt : uatt;
    const float* rel  = side ? irel : urel;
    int l = tid >> 7, a = (tid >> 6) & 1, kk = tid & 63;
    float s = 0.f;
    for (int c = 0; c < 64; c++) s += W[l * 4096 + kk * 64 + c] * att[l * 192 + a * 64 + c];
    waA[((side * 2 + l) * 2 + a) * 64 + kk] = s;
    if (tid < 4){
      int l2 = tid >> 1, a2 = tid & 1;
      float sb = 0.f;
      for (int c = 0; c < 64; c++) sb += bias[l2 * 64 + c] * att[l2 * 192 + a2 * 64 + c];
      ba[(side * 2 + l2) * 2 + a2] = sb;
    }
    if (tid >= 4 && tid < 12){
      int id = tid - 4, l2 = id >> 2, tt = id & 3;
      float sr = 0.f;
      for (int c = 0; c < 64; c++) sr += rel[l2 * 256 + tt * 64 + c] * att[l2 * 192 + 128 + c];
      rtab[(side * 2 + l2) * 4 + tt] = sr;
    }
  }
}

// ---------------- per-interaction prep: rep (inter) + queries (both sides) ----------------
__global__ void k_prep(const int* __restrict__ uid, const int* __restrict__ iid,
                       const float* __restrict__ uemb, const float* __restrict__ iemb,
                       const float* __restrict__ uiW, const float* __restrict__ uib,
                       const float* __restrict__ iiW, const float* __restrict__ iib,
                       const float* __restrict__ utW, const float* __restrict__ utb,
                       const float* __restrict__ itW, const float* __restrict__ itb,
                       float* __restrict__ xfm, float* __restrict__ q){
  int lane = threadIdx.x & 63, w = threadIdx.x >> 6;
  int b = blockIdx.x * 4 + w;                     // [0, 2NB)
  int side = b >= NB;
  int lb = b - side * NB;
  const int* ids = side ? iid : uid;
  const float* emb = side ? iemb : uemb;
  const float* interW = side ? iiW : uiW;
  const float* interB = side ? iib : uib;
  const float* transW = side ? itW : utW;
  const float* transB = side ? itb : utb;
  int repOff = side ? 192 : 0;
  float xe = emb[(long)ids[lb] * 64 + lane];
  float o = interB[lane];
#pragma unroll
  for (int k = 0; k < 64; k++) o += __shfl(xe, k, 64) * interW[k * 64 + lane];
  xfm[lb * 384 + repOff + lane] = fmaxf(o, 0.f);
  for (int l = 0; l < 2; l++){
    float t = transB[l * 64 + lane];
#pragma unroll
    for (int k = 0; k < 64; k++) t += __shfl(xe, k, 64) * transW[l * 4096 + k * 64 + lane];
    q[((size_t)(side * 2 + l) * NB + lb) * 64 + lane] = fmaxf(t, 0.f);
  }
}

// ---------------- MFMA: h = x @ W + b (bf16 out) ; fused a0/a1 = x.waA + ba ----------------
__global__ __launch_bounds__(256) void k_gemm_h(
    const short* __restrict__ x, const short* __restrict__ wtab,
    const int* __restrict__ u_nodes, const int* __restrict__ i_nodes,
    const short8* __restrict__ cfrag,
    const float* __restrict__ cub, const float* __restrict__ cib, int l,
    const float* __restrict__ waA_all, const float* __restrict__ ba_all,
    short* __restrict__ h, float* __restrict__ a0, float* __restrict__ a1){
  int bid = blockIdx.x;
  int side = bid >= (NN / 128);
  const short8* wfrag = cfrag + (side * 2 + l) * 512;
  const float* bias = (side ? cib : cub) + l * 64;
  const float* waA = waA_all + (side * 2 + l) * 128;
  const float* ba = ba_all + (side * 2 + l) * 2;
  const int* nodes = side ? i_nodes : u_nodes;
  int lane = threadIdx.x & 63, w = threadIdx.x >> 6;
  int m = lane & 15, q = lane >> 4;
  short8 Bf[4][2];
#pragma unroll
  for (int t = 0; t < 4; t++)
#pragma unroll
    for (int hh = 0; hh < 2; hh++)
      Bf[t][hh] = wfrag[(t * 2 + hh) * 64 + lane];
  float bs[4];
#pragma unroll
  for (int t = 0; t < 4; t++) bs[t] = bias[t * 16 + m];
  float w0[16], w1[16];
#pragma unroll
  for (int j = 0; j < 8; j++){
    w0[j]     = waA[q * 8 + j];
    w0[8 + j] = waA[32 + q * 8 + j];
    w1[j]     = waA[64 + q * 8 + j];
    w1[8 + j] = waA[96 + q * 8 + j];
  }
  float ba0 = ba[0], ba1 = ba[1];
  long n0 = (long)bid * 128 + w * 32;
  for (int rb = 0; rb < 2; rb++, n0 += 16){
    const short8* xr;
    if (l == 0){
      long local = n0 + m - (long)side * NN;
      xr = (const short8*)(wtab + (long)nodes[local] * 64);
    } else {
      xr = (const short8*)(x + (n0 + m) * 64);
    }
    short8 A0 = xr[q];
    short8 A1 = xr[q + 4];
    f32x4 acc[4];
#pragma unroll
    for (int t = 0; t < 4; t++){
      acc[t] = (f32x4){bs[t], bs[t], bs[t], bs[t]};
      acc[t] = __builtin_amdgcn_mfma_f32_16x16x32_bf16(A0, Bf[t][0], acc[t], 0, 0, 0);
      acc[t] = __builtin_amdgcn_mfma_f32_16x16x32_bf16(A1, Bf[t][1], acc[t], 0, 0, 0);
    }
#pragma unroll
    for (int t = 0; t < 4; t++)
#pragma unroll
      for (int r = 0; r < 4; r++)
        h[(n0 + q * 4 + r) * 64 + t * 16 + m] = f2bs(acc[t][r]);
    float p0 = 0.f, p1 = 0.f;
#pragma unroll
    for (int j = 0; j < 8; j++){
      float va = bs2f(A0[j]);
      float vb = bs2f(A1[j]);
      p0 += va * w0[j] + vb * w0[8 + j];
      p1 += va * w1[j] + vb * w1[8 + j];
    }
    p0 += __shfl_xor(p0, 16, 64); p0 += __shfl_xor(p0, 32, 64);
    p1 += __shfl_xor(p1, 16, 64); p1 += __shfl_xor(p1, 32, 64);
    if (q == 0){ a0[n0 + m] = p0 + ba0; a1[n0 + m] = p1 + ba1; }
  }
}

// ---------------- edge weights (one pass): alpha[e] = exp(leaky(logit)), inv_den[n] ----------------
__global__ void k_alpha(const int* __restrict__ rowptr, const int* __restrict__ pedge,
                        const float* __restrict__ a0, const float* __restrict__ a1,
                        const float* __restrict__ rtab, int l,
                        float* __restrict__ alpha, float* __restrict__ inv_den){
  int n = blockIdx.x * 256 + threadIdx.x;        // [0, 2NN)
  int side = n >= NN;
  const float* rt = rtab + (side * 2 + l) * 4;
  float rt0 = rt[0], rt1 = rt[1], rt2 = rt[2], rt3 = rt[3];
  int s0 = rowptr[n], s1 = rowptr[n + 1];
  float a1n = a1[n];
  float den = 0.f;
  for (int e = s0; e < s1; e++){
    int pe = pedge[e];
    int src = pe & 0x3FFFF;
    int et = (pe >> 18) & 3;
    float r = (et & 2) ? ((et & 1) ? rt3 : rt2) : ((et & 1) ? rt1 : rt0);
    float v = a0[src] + a1n + r;
    v = (v > 0.f) ? v : 0.2f * v;
    float wv = __expf(v);
    alpha[e] = wv;
    den += wv;
  }
  inv_den[n] = 1.f / (den + 1e-16f);
}

// ---------------- GAT aggregation: wave per 8 dst nodes; quarter-wave per edge ----------------
__global__ __launch_bounds__(256) void k_agg(
    const int* __restrict__ rowptr, const int* __restrict__ pedge,
    const float* __restrict__ alpha, const float* __restrict__ inv_den,
    const unsigned* __restrict__ h32, unsigned* __restrict__ xo32){
  int lane = threadIdx.x & 63, w = threadIdx.x >> 6;
  int nb = (blockIdx.x * 4 + w) * 8;              // 8 nodes per wave
  int q = lane >> 4, cl = lane & 15;              // quarter, uint2 index within 128B row
  int rp = (lane < 9) ? rowptr[nb + lane] : 0;
  float idn = (lane < 8) ? inv_den[nb + lane] : 0.f;
  int rp0 = __shfl(rp, 0, 64);
  int rp8 = __shfl(rp, 8, 64);
  int tot = min(rp8 - rp0, 64);
  // coalesced preload of the wave's edge window
  int psrc = 0; float pal = 0.f;
  if (lane < tot){
    psrc = pedge[rp0 + lane] & 0x3FFFF;
    pal  = alpha[rp0 + lane];
  }
  const uint2* h2 = (const uint2*)h32;
#pragma unroll
  for (int k = 0; k < 8; k++){
    int r0 = __shfl(rp, k, 64), r1 = __shfl(rp, k + 1, 64);
    float ax0 = 0.f, ay0 = 0.f, ax1 = 0.f, ay1 = 0.f;
    for (int j = r0; j < r1; j += 4){
      int e = j + q;
      bool ok = e < r1;
      int idx = e - rp0;
      int idxc = min(idx, 63);
      int s = __shfl(psrc, idxc, 64);
      float al = __shfl(pal, idxc, 64);
      if (idx >= 64){                 // rare spill past preload window
        int pe = pedge[e];
        s = pe & 0x3FFFF;
        al = alpha[e];
      }
      if (ok){
        uint2 v = h2[(long)s * 16 + cl];
        ax0 += al * ulo2f(v.x); ay0 += al * uhi2f(v.x);
        ax1 += al * ulo2f(v.y); ay1 += al * uhi2f(v.y);
      }
    }
    ax0 += __shfl_xor(ax0, 16, 64); ax0 += __shfl_xor(ax0, 32, 64);
    ay0 += __shfl_xor(ay0, 16, 64); ay0 += __shfl_xor(ay0, 32, 64);
    ax1 += __shfl_xor(ax1, 16, 64); ax1 += __shfl_xor(ax1, 32, 64);
    ay1 += __shfl_xor(ay1, 16, 64); ay1 += __shfl_xor(ay1, 32, 64);
    float dk = __shfl(idn, k, 64);
    if (q == 0){
      uint2 o;
      o.x = fpack(fmaxf(ax0 * dk, 0.f), fmaxf(ay0 * dk, 0.f));
      o.y = fpack(fmaxf(ax1 * dk, 0.f), fmaxf(ay1 * dk, 0.f));
      ((uint2*)xo32)[(long)(nb + k) * 16 + cl] = o;
    }
  }
}

// ---------------- fused: y=x@poolW (MFMA), gate, gmp(x*gate), trans_w ----------------
__global__ __launch_bounds__(256) void k_scorepool(
    const short* __restrict__ x, const short8* __restrict__ frag,
    const float* __restrict__ qbuf, int l, const float* __restrict__ twW_all,
    const float* __restrict__ twb_all, float* __restrict__ xfm){
  __shared__ float gates[128];
  __shared__ float red[4][64];
  int b = blockIdx.x;                              // [0, 2NB)
  int side = b >= NB;
  int g = b - side * NB;
  const short8* pfrag = frag + 4 * 512;
  const float* q = qbuf + ((size_t)(side * 2 + l) * NB + g) * 64;
  const float* twW = twW_all + l * 4096;
  const float* twb = twb_all + l * 64;
  int off = (side ? 256 : 64) + l * 64;
  long base = (long)side * NN + (long)g * 128;
  int tid = threadIdx.x, lane = tid & 63, w = tid >> 6;
  int m = lane & 15, qd = lane >> 4;
  short8 Bf[4][2];
#pragma unroll
  for (int t = 0; t < 4; t++)
#pragma unroll
    for (int hh = 0; hh < 2; hh++)
      Bf[t][hh] = pfrag[(t * 2 + hh) * 64 + lane];
  float qv[4];
#pragma unroll
  for (int t = 0; t < 4; t++) qv[t] = q[t * 16 + m];
  for (int rb = 0; rb < 2; rb++){
    long n0 = base + w * 32 + rb * 16;
    const short8* xr = (const short8*)(x + (n0 + m) * 64);
    short8 A0 = xr[qd];
    short8 A1 = xr[qd + 4];
    f32x4 acc[4];
#pragma unroll
    for (int t = 0; t < 4; t++){
      acc[t] = (f32x4){0.f, 0.f, 0.f, 0.f};
      acc[t] = __builtin_amdgcn_mfma_f32_16x16x32_bf16(A0, Bf[t][0], acc[t], 0, 0, 0);
      acc[t] = __builtin_amdgcn_mfma_f32_16x16x32_bf16(A1, Bf[t][1], acc[t], 0, 0, 0);
    }
#pragma unroll
    for (int r = 0; r < 4; r++){
      float p = acc[0][r] * qv[0] + acc[1][r] * qv[1] + acc[2][r] * qv[2] + acc[3][r] * qv[3];
      p += __shfl_xor(p, 1, 64); p += __shfl_xor(p, 2, 64);
      p += __shfl_xor(p, 4, 64); p += __shfl_xor(p, 8, 64);
      if (m == 0)
        gates[w * 32 + rb * 16 + qd * 4 + r] = 1.f / (1.f + __expf(-p * 0.125f));
    }
  }
  __syncthreads();
  const unsigned* x32 = (const unsigned*)x;
  int c = lane & 31, half = lane >> 5;
  float mxx = 0.f, mxy = 0.f;
  for (int p = 0; p < 16; p++){
    int nn = w * 32 + 2 * p + half;
    unsigned v = x32[(base + nn) * 32 + c];
    float gt = gates[nn];
    mxx = fmaxf(mxx, ulo2f(v) * gt);
    mxy = fmaxf(mxy, uhi2f(v) * gt);
  }
  mxx = fmaxf(mxx, __shfl_xor(mxx, 32, 64));
  mxy = fmaxf(mxy, __shfl_xor(mxy, 32, 64));
  if (half == 0){ red[w][2 * c] = mxx; red[w][2 * c + 1] = mxy; }
  __syncthreads();
  if (tid < 64){
    float p = fmaxf(fmaxf(red[0][tid], red[1][tid]), fmaxf(red[2][tid], red[3][tid]));
    float o = twb[tid];
    red[0][tid] = p;
    __syncwarp();
    for (int d = 0; d < 64; d++) o += red[0][d] * twW[d * 64 + tid];
    xfm[g * 384 + off + tid] = fmaxf(o, 0.f);
  }
}

// ---------------- FM head: 4 graphs per block, V streamed once per block ----------------
__global__ __launch_bounds__(384) void k_fm(
    const float* __restrict__ xfm, const float* __restrict__ V,
    const float* __restrict__ fw, const float* __restrict__ bu,
    const float* __restrict__ bi, const float* __restrict__ b0,
    const int* __restrict__ uid, const int* __restrict__ iid,
    float* __restrict__ out){
  __shared__ float xsh[4][384];
  __shared__ float xsq[4][384];
  __shared__ float part[4][384];
  int j = threadIdx.x;                 // 0..383 = FM column
  int g0 = blockIdx.x * 4;
#pragma unroll
  for (int b = 0; b < 4; b++){
    float xv_ = xfm[(g0 + b) * 384 + j];
    xsh[b][j] = xv_;
    xsq[b][j] = xv_ * xv_;
  }
  __syncthreads();
  float xv[4] = {0.f, 0.f, 0.f, 0.f};
  float vv[4] = {0.f, 0.f, 0.f, 0.f};
  for (int k = 0; k < 384; k++){
    float v = V[(size_t)k * 384 + j];
    float v2 = v * v;
#pragma unroll
    for (int b = 0; b < 4; b++){
      xv[b] = fmaf(xsh[b][k], v, xv[b]);
      vv[b] = fmaf(xsq[b][k], v2, vv[b]);
    }
  }
  float fwj = fw[j];
#pragma unroll
  for (int b = 0; b < 4; b++)
    part[b][j] = 0.5f * (xv[b] * xv[b] - vv[b]) + xsh[b][j] * fwj;
  __syncthreads();
  int w = j >> 6, lane = j & 63;
  if (w < 4){
    float s = part[w][lane] + part[w][lane + 64] + part[w][lane + 128] +
              part[w][lane + 192] + part[w][lane + 256] + part[w][lane + 320];
    s = wsum(s);
    if (lane == 0){
      int b = g0 + w;
      out[b] = s + bu[uid[b]] + bi[iid[b]] + b0[0];
    }
  }
}

extern "C" void kernel_launch(void* const* d_in, const int* in_sizes, int n_in,
                              void* d_out, int out_size, void* d_ws, size_t ws_size,
                              hipStream_t stream) {
  const int* uid      = (const int*)d_in[0];
  const int* iid      = (const int*)d_in[1];
  const int* u_nodes  = (const int*)d_in[2];
  const int* i_nodes  = (const int*)d_in[3];
  const int* u_ei     = (const int*)d_in[4];
  const int* i_ei     = (const int*)d_in[5];
  const int* u_et     = (const int*)d_in[6];
  const int* i_et     = (const int*)d_in[7];
  const float* user_emb = (const float*)d_in[10];
  const float* item_emb = (const float*)d_in[11];
  const float* word_emb = (const float*)d_in[12];
  const float* trans_u_W = (const float*)d_in[13];
  const float* trans_u_b = (const float*)d_in[14];
  const float* trans_i_W = (const float*)d_in[15];
  const float* trans_i_b = (const float*)d_in[16];
  const float* trans_w_W = (const float*)d_in[17];
  const float* trans_w_b = (const float*)d_in[18];
  const float* inter_u_W = (const float*)d_in[19];
  const float* inter_u_b = (const float*)d_in[20];
  const float* inter_i_W = (const float*)d_in[21];
  const float* inter_i_b = (const float*)d_in[22];
  const float* conv_u_W  = (const float*)d_in[23];
  const float* conv_u_b  = (const float*)d_in[24];
  const float* conv_u_att= (const float*)d_in[25];
  const float* conv_u_rel= (const float*)d_in[26];
  const float* conv_i_W  = (const float*)d_in[27];
  const float* conv_i_b  = (const float*)d_in[28];
  const float* conv_i_att= (const float*)d_in[29];
  const float* conv_i_rel= (const float*)d_in[30];
  const float* pool_W    = (const float*)d_in[31];
  const float* fm_w      = (const float*)d_in[32];
  const float* fm_V      = (const float*)d_in[33];
  const float* fm_bias_u = (const float*)d_in[34];
  const float* fm_bias_i = (const float*)d_in[35];
  const float* fm_bias   = (const float*)d_in[36];
  float* out = (float*)d_out;
  int nwords32 = in_sizes[12] / 2;   // fp32 elements / 2 = packed uints

  // workspace carve-up (all chunks multiples of 16 B)
  char* w = (char*)d_ws;
  short* X0   = (short*)w;          w += (size_t)2 * NN * 64 * 2;   // 32 MB
  short* X1   = (short*)w;          w += (size_t)2 * NN * 64 * 2;   // 32 MB
  short* H    = (short*)w;          w += (size_t)2 * NN * 64 * 2;   // 32 MB
  short* wtab = (short*)w;          w += (size_t)in_sizes[12] * 2;  // bf16 word table
  int* pedge  = (int*)w;            w += (size_t)2 * NE * 4;        // 4 MB
  float* alpha= (float*)w;          w += (size_t)2 * NE * 4;        // 4 MB
  float* a0   = (float*)w;          w += (size_t)2 * NN * 4;
  float* a1   = (float*)w;          w += (size_t)2 * NN * 4;
  float* invd = (float*)w;          w += (size_t)2 * NN * 4;
  int* rowptr = (int*)w;            w += (size_t)(2 * NN + 256) * 4;
  int* cursor = (int*)w;            w += (size_t)2 * NN * 4;
  int* cnt    = (int*)w;            w += (size_t)2 * NN * 4;
  int* bsum   = (int*)w;            w += 1024 * 4;
  short8* frag = (short8*)w;        w += (size_t)5 * 512 * 16;      // 5 matrices
  float* waA  = (float*)w;          w += 2 * 2 * 2 * 64 * 4;
  float* ba   = (float*)w;          w += 64;
  float* rtab = (float*)w;          w += 64;
  float* qbuf = (float*)w;          w += (size_t)4 * NB * 64 * 4;
  float* xfm  = (float*)w;          w += (size_t)NB * 384 * 4;

  k_wprep  <<<12, 256, 0, stream>>>(conv_u_W, conv_i_W, pool_W, conv_u_b, conv_i_b,
                                    conv_u_att, conv_i_att, conv_u_rel, conv_i_rel,
                                    frag, waA, ba, rtab);
  k_wconv  <<<(nwords32 + 255) / 256, 256, 0, stream>>>(word_emb, (unsigned*)wtab,
                                                        nwords32);
  k_zero   <<<2 * NN / 256, 256, 0, stream>>>(cnt);
  k_hist   <<<8 * (2 * NE / 256), 256, 0, stream>>>(u_ei, i_ei, cnt);
  k_scan1  <<<2 * NN / 256, 256, 0, stream>>>(cnt, rowptr, bsum);
  k_scan2  <<<1, 1024, 0, stream>>>(bsum);
  k_scan3  <<<2 * NN / 256, 256, 0, stream>>>(rowptr, bsum, cursor);
  k_scatter<<<8 * (2 * NE / 256), 256, 0, stream>>>(u_ei, i_ei, u_et, i_et,
                                                    cursor, pedge);
  k_prep   <<<2 * NB / 4, 256, 0, stream>>>(uid, iid, user_emb, item_emb,
                                            inter_u_W, inter_u_b, inter_i_W, inter_i_b,
                                            trans_u_W, trans_u_b, trans_i_W, trans_i_b,
                                            xfm, qbuf);

  short* Xin = X0;   // l=0 ignores Xin (reads wtab)
  for (int l = 0; l < 2; ++l){
    short* Xout = l == 0 ? X0 : X1;
    k_gemm_h<<<2 * NN / 128, 256, 0, stream>>>(Xin, wtab, u_nodes, i_nodes, frag,
                                               conv_u_b, conv_i_b, l,
                                               waA, ba, H, a0, a1);
    k_alpha <<<2 * NN / 256, 256, 0, stream>>>(rowptr, pedge, a0, a1, rtab, l,
                                               alpha, invd);
    k_agg   <<<2 * NN / 32, 256, 0, stream>>>(rowptr, pedge, alpha, invd,
                                              (const unsigned*)H, (unsigned*)Xout);
    k_scorepool<<<2 * NB, 256, 0, stream>>>(Xout, frag, qbuf, l,
                                            trans_w_W, trans_w_b, xfm);
    Xin = Xout;
  }

  k_fm<<<NB / 4, 384, 0, stream>>>(xfm, fm_V, fm_w, fm_bias_u, fm_bias_i, fm_bias,
                                   uid, iid, out);
}

// Round 8
// 463.099 us; speedup vs baseline: 1.2264x; 1.0420x over previous
//
#include <hip/hip_runtime.h>
#include <hip/hip_bf16.h>

#define NN 131072   // nodes per side
#define NE 524288   // edges per side
#define NB 1024     // batch (graphs per side)

typedef __attribute__((ext_vector_type(8))) short short8;   // 8 bf16
typedef __attribute__((ext_vector_type(4))) float f32x4;

__device__ __forceinline__ float wsum(float v){
#pragma unroll
  for (int o = 32; o > 0; o >>= 1) v += __shfl_xor(v, o, 64);
  return v;
}
__device__ __forceinline__ short f2bs(float f){
  __hip_bfloat16 t = __float2bfloat16(f);
  union { __hip_bfloat16 b; short s; } u; u.b = t; return u.s;
}
__device__ __forceinline__ float bs2f(short s){
  return __uint_as_float(((unsigned)(unsigned short)s) << 16);
}
__device__ __forceinline__ float ulo2f(unsigned v){ return __uint_as_float(v << 16); }
__device__ __forceinline__ float uhi2f(unsigned v){ return __uint_as_float(v & 0xFFFF0000u); }
__device__ __forceinline__ unsigned fpack(float x, float y){
  return (unsigned)(unsigned short)f2bs(x) | ((unsigned)(unsigned short)f2bs(y) << 16);
}

// ---------------- CSR build (both sides; global node = side*NN + n) ----------------
// XCD-partitioned histogram: block b only counts dsts in partition (b&7).
__global__ void k_hist(const int* __restrict__ u_ei, const int* __restrict__ i_ei,
                       int* __restrict__ cnt){
  int b = blockIdx.x;
  int x = b & 7;
  int ee = (b >> 3) * 256 + threadIdx.x;         // [0, 2NE)
  int side = ee >= NE;
  int e = ee - side * NE;
  const int* ei = side ? i_ei : u_ei;
  int dst = ei[NE + e] + side * NN;
  if ((dst >> 15) == x) atomicAdd(&cnt[dst], 1);
}

__global__ void k_scan1(const int* __restrict__ cnt, int* __restrict__ rowptr,
                        int* __restrict__ bsum){
  __shared__ int sh[256];
  int i = blockIdx.x * 256 + threadIdx.x;
  int v = cnt[i];
  sh[threadIdx.x] = v; __syncthreads();
  for (int off = 1; off < 256; off <<= 1){
    int t = (threadIdx.x >= off) ? sh[threadIdx.x - off] : 0;
    __syncthreads();
    sh[threadIdx.x] += t;
    __syncthreads();
  }
  int incl = sh[threadIdx.x];
  rowptr[i] = incl - v;
  if (threadIdx.x == 255) bsum[blockIdx.x] = incl;
}

__global__ void k_scan2(int* __restrict__ bsum){
  __shared__ int sh[1024];
  int v = bsum[threadIdx.x];
  sh[threadIdx.x] = v; __syncthreads();
  for (int off = 1; off < 1024; off <<= 1){
    int t = (threadIdx.x >= off) ? sh[threadIdx.x - off] : 0;
    __syncthreads();
    sh[threadIdx.x] += t;
    __syncthreads();
  }
  bsum[threadIdx.x] = sh[threadIdx.x] - v;  // exclusive
}

__global__ void k_scan3(int* __restrict__ rowptr, const int* __restrict__ bsum,
                        int* __restrict__ cursor){
  int i = blockIdx.x * 256 + threadIdx.x;
  int v = rowptr[i] + bsum[blockIdx.x];
  rowptr[i] = v;
  cursor[i] = v;
  if (i == 0) rowptr[2 * NN] = 2 * NE;
}

// XCD-partitioned scatter.
__global__ void k_scatter(const int* __restrict__ u_ei, const int* __restrict__ i_ei,
                          const int* __restrict__ u_et, const int* __restrict__ i_et,
                          int* __restrict__ cursor, int* __restrict__ pedge){
  int b = blockIdx.x;
  int x = b & 7;
  int ee = (b >> 3) * 256 + threadIdx.x;
  int side = ee >= NE;
  int e = ee - side * NE;
  const int* ei = side ? i_ei : u_ei;
  int dst = ei[NE + e] + side * NN;
  if ((dst >> 15) == x){
    const int* et = side ? i_et : u_et;
    int src = ei[e] + side * NN;
    int p = atomicAdd(&cursor[dst], 1);
    pedge[p] = src | (et[e] << 18);
  }
}

// ---------------- mega prep: wprep(12) | wconv | zero cnt | prep ----------------
__global__ void k_mega(int wconvB,
                       const float* __restrict__ wemb, unsigned* __restrict__ wtab,
                       int n32, int* __restrict__ cnt,
                       const float* __restrict__ cuW, const float* __restrict__ ciW,
                       const float* __restrict__ pW,
                       const float* __restrict__ cub, const float* __restrict__ cib,
                       const float* __restrict__ uatt, const float* __restrict__ iatt,
                       const float* __restrict__ urel, const float* __restrict__ irel,
                       short8* __restrict__ frag, float* __restrict__ waA,
                       float* __restrict__ ba, float* __restrict__ rtab,
                       const int* __restrict__ uid, const int* __restrict__ iid,
                       const float* __restrict__ uemb, const float* __restrict__ iemb,
                       const float* __restrict__ uiW, const float* __restrict__ uib,
                       const float* __restrict__ iiW, const float* __restrict__ iib,
                       const float* __restrict__ utW, const float* __restrict__ utb,
                       const float* __restrict__ itW, const float* __restrict__ itb,
                       float* __restrict__ xfm, float* __restrict__ q){
  int blk = blockIdx.x, tid = threadIdx.x;
  if (blk < 10){
    // MFMA B-frag packing for 5 matrices
    int mat = blk >> 1;
    const float* W = mat < 2 ? cuW + mat * 4096 : (mat < 4 ? ciW + (mat - 2) * 4096 : pW);
    int g = (blk & 1) * 256 + tid;     // [0,512)
    int lane = g & 63, rest = g >> 6;
    int hh = rest & 1, t = rest >> 1;
    int m = lane & 15, qq = lane >> 4;
    short8 v;
#pragma unroll
    for (int j = 0; j < 8; j++)
      v[j] = f2bs(W[(hh * 32 + qq * 8 + j) * 64 + (t * 16 + m)]);
    frag[mat * 512 + g] = v;
  } else if (blk < 12){
    int side = blk - 10;
    const float* W    = side ? ciW : cuW;
    const float* bias = side ? cib : cub;
    const float* att  = side ? iatt : uatt;
    const float* rel  = side ? irel : urel;
    int l = tid >> 7, a = (tid >> 6) & 1, kk = tid & 63;
    float s = 0.f;
    for (int c = 0; c < 64; c++) s += W[l * 4096 + kk * 64 + c] * att[l * 192 + a * 64 + c];
    waA[((side * 2 + l) * 2 + a) * 64 + kk] = s;
    if (tid < 4){
      int l2 = tid >> 1, a2 = tid & 1;
      float sb = 0.f;
      for (int c = 0; c < 64; c++) sb += bias[l2 * 64 + c] * att[l2 * 192 + a2 * 64 + c];
      ba[(side * 2 + l2) * 2 + a2] = sb;
    }
    if (tid >= 4 && tid < 12){
      int id = tid - 4, l2 = id >> 2, tt = id & 3;
      float sr = 0.f;
      for (int c = 0; c < 64; c++) sr += rel[l2 * 256 + tt * 64 + c] * att[l2 * 192 + 128 + c];
      rtab[(side * 2 + l2) * 4 + tt] = sr;
    }
  } else if (blk < 12 + wconvB){
    int id = (blk - 12) * 256 + tid;
    if (id < n32){
      const float2* src = (const float2*)wemb;
      float2 v = src[id];
      wtab[id] = fpack(v.x, v.y);
    }
  } else if (blk < 12 + wconvB + 2 * NN / 256){
    cnt[(blk - 12 - wconvB) * 256 + tid] = 0;
  } else {
    int lane = tid & 63, w = tid >> 6;
    int b = (blk - 12 - wconvB - 2 * NN / 256) * 4 + w;   // [0, 2NB)
    int side = b >= NB;
    int lb = b - side * NB;
    const int* ids = side ? iid : uid;
    const float* emb = side ? iemb : uemb;
    const float* interW = side ? iiW : uiW;
    const float* interB = side ? iib : uib;
    const float* transW = side ? itW : utW;
    const float* transB = side ? itb : utb;
    int repOff = side ? 192 : 0;
    float xe = emb[(long)ids[lb] * 64 + lane];
    float o = interB[lane];
#pragma unroll
    for (int k = 0; k < 64; k++) o += __shfl(xe, k, 64) * interW[k * 64 + lane];
    xfm[lb * 384 + repOff + lane] = fmaxf(o, 0.f);
    for (int l = 0; l < 2; l++){
      float t = transB[l * 64 + lane];
#pragma unroll
      for (int k = 0; k < 64; k++) t += __shfl(xe, k, 64) * transW[l * 4096 + k * 64 + lane];
      q[((size_t)(side * 2 + l) * NB + lb) * 64 + lane] = fmaxf(t, 0.f);
    }
  }
}

// ---------------- device fn: MFMA h = x@W + b (bf16 out); fused a0/a1 ----------------
__device__ __forceinline__ void dev_gemm(
    int bid, const short* __restrict__ x, const short* __restrict__ wtab,
    const int* __restrict__ u_nodes, const int* __restrict__ i_nodes,
    const short8* __restrict__ cfrag,
    const float* __restrict__ cub, const float* __restrict__ cib, int l,
    const float* __restrict__ waA_all, const float* __restrict__ ba_all,
    short* __restrict__ h, float* __restrict__ a0, float* __restrict__ a1){
  int side = bid >= (NN / 128);
  const short8* wfrag = cfrag + (side * 2 + l) * 512;
  const float* bias = (side ? cib : cub) + l * 64;
  const float* waA = waA_all + (side * 2 + l) * 128;
  const float* ba = ba_all + (side * 2 + l) * 2;
  const int* nodes = side ? i_nodes : u_nodes;
  int lane = threadIdx.x & 63, w = threadIdx.x >> 6;
  int m = lane & 15, q = lane >> 4;
  short8 Bf[4][2];
#pragma unroll
  for (int t = 0; t < 4; t++)
#pragma unroll
    for (int hh = 0; hh < 2; hh++)
      Bf[t][hh] = wfrag[(t * 2 + hh) * 64 + lane];
  float bs[4];
#pragma unroll
  for (int t = 0; t < 4; t++) bs[t] = bias[t * 16 + m];
  float w0[16], w1[16];
#pragma unroll
  for (int j = 0; j < 8; j++){
    w0[j]     = waA[q * 8 + j];
    w0[8 + j] = waA[32 + q * 8 + j];
    w1[j]     = waA[64 + q * 8 + j];
    w1[8 + j] = waA[96 + q * 8 + j];
  }
  float ba0 = ba[0], ba1 = ba[1];
  long n0 = (long)bid * 128 + w * 32;
  for (int rb = 0; rb < 2; rb++, n0 += 16){
    const short8* xr;
    if (l == 0){
      long local = n0 + m - (long)side * NN;
      xr = (const short8*)(wtab + (long)nodes[local] * 64);
    } else {
      xr = (const short8*)(x + (n0 + m) * 64);
    }
    short8 A0 = xr[q];
    short8 A1 = xr[q + 4];
    f32x4 acc[4];
#pragma unroll
    for (int t = 0; t < 4; t++){
      acc[t] = (f32x4){bs[t], bs[t], bs[t], bs[t]};
      acc[t] = __builtin_amdgcn_mfma_f32_16x16x32_bf16(A0, Bf[t][0], acc[t], 0, 0, 0);
      acc[t] = __builtin_amdgcn_mfma_f32_16x16x32_bf16(A1, Bf[t][1], acc[t], 0, 0, 0);
    }
#pragma unroll
    for (int t = 0; t < 4; t++)
#pragma unroll
      for (int r = 0; r < 4; r++)
        h[(n0 + q * 4 + r) * 64 + t * 16 + m] = f2bs(acc[t][r]);
    float p0 = 0.f, p1 = 0.f;
#pragma unroll
    for (int j = 0; j < 8; j++){
      float va = bs2f(A0[j]);
      float vb = bs2f(A1[j]);
      p0 += va * w0[j] + vb * w0[8 + j];
      p1 += va * w1[j] + vb * w1[8 + j];
    }
    p0 += __shfl_xor(p0, 16, 64); p0 += __shfl_xor(p0, 32, 64);
    p1 += __shfl_xor(p1, 16, 64); p1 += __shfl_xor(p1, 32, 64);
    if (q == 0){ a0[n0 + m] = p0 + ba0; a1[n0 + m] = p1 + ba1; }
  }
}

// ---------------- device fn: y=x@poolW (MFMA), gate, gmp, trans_w ----------------
__device__ __forceinline__ void dev_scorepool(
    int b, const short* __restrict__ x, const short8* __restrict__ frag,
    const float* __restrict__ qbuf, int l, const float* __restrict__ twW_all,
    const float* __restrict__ twb_all, float* __restrict__ xfm){
  __shared__ float gates[128];
  __shared__ float red[4][64];
  int side = b >= NB;
  int g = b - side * NB;
  const short8* pfrag = frag + 4 * 512;
  const float* q = qbuf + ((size_t)(side * 2 + l) * NB + g) * 64;
  const float* twW = twW_all + l * 4096;
  const float* twb = twb_all + l * 64;
  int off = (side ? 256 : 64) + l * 64;
  long base = (long)side * NN + (long)g * 128;
  int tid = threadIdx.x, lane = tid & 63, w = tid >> 6;
  int m = lane & 15, qd = lane >> 4;
  short8 Bf[4][2];
#pragma unroll
  for (int t = 0; t < 4; t++)
#pragma unroll
    for (int hh = 0; hh < 2; hh++)
      Bf[t][hh] = pfrag[(t * 2 + hh) * 64 + lane];
  float qv[4];
#pragma unroll
  for (int t = 0; t < 4; t++) qv[t] = q[t * 16 + m];
  for (int rb = 0; rb < 2; rb++){
    long n0 = base + w * 32 + rb * 16;
    const short8* xr = (const short8*)(x + (n0 + m) * 64);
    short8 A0 = xr[qd];
    short8 A1 = xr[qd + 4];
    f32x4 acc[4];
#pragma unroll
    for (int t = 0; t < 4; t++){
      acc[t] = (f32x4){0.f, 0.f, 0.f, 0.f};
      acc[t] = __builtin_amdgcn_mfma_f32_16x16x32_bf16(A0, Bf[t][0], acc[t], 0, 0, 0);
      acc[t] = __builtin_amdgcn_mfma_f32_16x16x32_bf16(A1, Bf[t][1], acc[t], 0, 0, 0);
    }
#pragma unroll
    for (int r = 0; r < 4; r++){
      float p = acc[0][r] * qv[0] + acc[1][r] * qv[1] + acc[2][r] * qv[2] + acc[3][r] * qv[3];
      p += __shfl_xor(p, 1, 64); p += __shfl_xor(p, 2, 64);
      p += __shfl_xor(p, 4, 64); p += __shfl_xor(p, 8, 64);
      if (m == 0)
        gates[w * 32 + rb * 16 + qd * 4 + r] = 1.f / (1.f + __expf(-p * 0.125f));
    }
  }
  __syncthreads();
  const unsigned* x32 = (const unsigned*)x;
  int c = lane & 31, half = lane >> 5;
  float mxx = 0.f, mxy = 0.f;
  for (int p = 0; p < 16; p++){
    int nn = w * 32 + 2 * p + half;
    unsigned v = x32[(base + nn) * 32 + c];
    float gt = gates[nn];
    mxx = fmaxf(mxx, ulo2f(v) * gt);
    mxy = fmaxf(mxy, uhi2f(v) * gt);
  }
  mxx = fmaxf(mxx, __shfl_xor(mxx, 32, 64));
  mxy = fmaxf(mxy, __shfl_xor(mxy, 32, 64));
  if (half == 0){ red[w][2 * c] = mxx; red[w][2 * c + 1] = mxy; }
  __syncthreads();
  if (tid < 64){
    float p = fmaxf(fmaxf(red[0][tid], red[1][tid]), fmaxf(red[2][tid], red[3][tid]));
    float o = twb[tid];
    red[0][tid] = p;
    __syncwarp();
    for (int d = 0; d < 64; d++) o += red[0][d] * twW[d * 64 + tid];
    xfm[g * 384 + off + tid] = fmaxf(o, 0.f);
  }
}

__global__ __launch_bounds__(256) void k_gemm_h(
    const short* __restrict__ x, const short* __restrict__ wtab,
    const int* __restrict__ u_nodes, const int* __restrict__ i_nodes,
    const short8* __restrict__ cfrag,
    const float* __restrict__ cub, const float* __restrict__ cib, int l,
    const float* __restrict__ waA_all, const float* __restrict__ ba_all,
    short* __restrict__ h, float* __restrict__ a0, float* __restrict__ a1){
  dev_gemm(blockIdx.x, x, wtab, u_nodes, i_nodes, cfrag, cub, cib, l,
           waA_all, ba_all, h, a0, a1);
}

__global__ __launch_bounds__(256) void k_scorepool(
    const short* __restrict__ x, const short8* __restrict__ frag,
    const float* __restrict__ qbuf, int l, const float* __restrict__ twW_all,
    const float* __restrict__ twb_all, float* __restrict__ xfm){
  dev_scorepool(blockIdx.x, x, frag, qbuf, l, twW_all, twb_all, xfm);
}

// co-dispatch: gemm_h(l=1) on blocks [0,2NN/128), scorepool(l=0) on the rest
__global__ __launch_bounds__(256) void k_gsp(
    const short* __restrict__ x, const short* __restrict__ wtab,
    const int* __restrict__ u_nodes, const int* __restrict__ i_nodes,
    const short8* __restrict__ frag,
    const float* __restrict__ cub, const float* __restrict__ cib,
    const float* __restrict__ waA_all, const float* __restrict__ ba_all,
    short* __restrict__ h, float* __restrict__ a0, float* __restrict__ a1,
    const float* __restrict__ qbuf, const float* __restrict__ twW_all,
    const float* __restrict__ twb_all, float* __restrict__ xfm){
  if (blockIdx.x < 2 * NN / 128)
    dev_gemm(blockIdx.x, x, wtab, u_nodes, i_nodes, frag, cub, cib, 1,
             waA_all, ba_all, h, a0, a1);
  else
    dev_scorepool(blockIdx.x - 2 * NN / 128, x, frag, qbuf, 0,
                  twW_all, twb_all, xfm);
}

// ---------------- GAT aggregation with fused edge-softmax ----------------
__global__ __launch_bounds__(256) void k_agg(
    const int* __restrict__ rowptr, const int* __restrict__ pedge,
    const float* __restrict__ a0, const float* __restrict__ a1,
    const float* __restrict__ rtab, int l,
    const unsigned* __restrict__ h32, unsigned* __restrict__ xo32){
  int lane = threadIdx.x & 63, w = threadIdx.x >> 6;
  int nb = (blockIdx.x * 4 + w) * 8;              // 8 nodes per wave
  int side = nb >= NN;
  const float* rt = rtab + (side * 2 + l) * 4;
  float rt0 = rt[0], rt1 = rt[1], rt2 = rt[2], rt3 = rt[3];
  int q = lane >> 4, cl = lane & 15;              // quarter, uint2 idx in 128B row
  int rp = (lane < 9) ? rowptr[nb + lane] : 0;
  float a1v = (lane < 8) ? a1[nb + lane] : 0.f;
  int rp0 = __shfl(rp, 0, 64);
  int rp8 = __shfl(rp, 8, 64);
  int tot = min(rp8 - rp0, 64);
  // coalesced preload of the wave's edge window + inline softmax numerator
  int eidx = rp0 + lane;
  int pe = (lane < tot) ? pedge[eidx] : 0;
  int psrc = pe & 0x3FFFF;
  float pa0 = (lane < tot) ? a0[psrc] : 0.f;
  int kn = 0;
#pragma unroll
  for (int t = 1; t < 8; t++)
    kn += (eidx >= __shfl(rp, t, 64)) ? 1 : 0;
  float a1n = __shfl(a1v, kn, 64);
  int pet = (pe >> 18) & 3;
  float rr = (pet & 2) ? ((pet & 1) ? rt3 : rt2) : ((pet & 1) ? rt1 : rt0);
  float vv = pa0 + a1n + rr;
  vv = (vv > 0.f) ? vv : 0.2f * vv;
  float pex = (lane < tot) ? __expf(vv) : 0.f;
  const uint2* h2 = (const uint2*)h32;
#pragma unroll
  for (int k = 0; k < 8; k++){
    int r0 = __shfl(rp, k, 64), r1 = __shfl(rp, k + 1, 64);
    float a1k = __shfl(a1v, k, 64);
    float ax0 = 0.f, ay0 = 0.f, ax1 = 0.f, ay1 = 0.f, den = 0.f;
    for (int j = r0; j < r1; j += 4){
      int e = j + q;
      bool ok = e < r1;
      int idx = e - rp0;
      int idxc = min(idx, 63);
      int s = __shfl(psrc, idxc, 64);
      float ex = __shfl(pex, idxc, 64);
      if (idx >= 64 && ok){           // rare spill past preload window
        int pe2 = pedge[e];
        s = pe2 & 0x3FFFF;
        int et2 = (pe2 >> 18) & 3;
        float r2 = (et2 & 2) ? ((et2 & 1) ? rt3 : rt2) : ((et2 & 1) ? rt1 : rt0);
        float v2 = a0[s] + a1k + r2;
        v2 = (v2 > 0.f) ? v2 : 0.2f * v2;
        ex = __expf(v2);
      }
      if (ok){
        uint2 v = h2[(long)s * 16 + cl];
        ax0 += ex * ulo2f(v.x); ay0 += ex * uhi2f(v.x);
        ax1 += ex * ulo2f(v.y); ay1 += ex * uhi2f(v.y);
        den += ex;
      }
    }
    ax0 += __shfl_xor(ax0, 16, 64); ax0 += __shfl_xor(ax0, 32, 64);
    ay0 += __shfl_xor(ay0, 16, 64); ay0 += __shfl_xor(ay0, 32, 64);
    ax1 += __shfl_xor(ax1, 16, 64); ax1 += __shfl_xor(ax1, 32, 64);
    ay1 += __shfl_xor(ay1, 16, 64); ay1 += __shfl_xor(ay1, 32, 64);
    den += __shfl_xor(den, 16, 64); den += __shfl_xor(den, 32, 64);
    float inv = 1.f / (den + 1e-16f);
    if (q == 0){
      uint2 o;
      o.x = fpack(fmaxf(ax0 * inv, 0.f), fmaxf(ay0 * inv, 0.f));
      o.y = fpack(fmaxf(ax1 * inv, 0.f), fmaxf(ay1 * inv, 0.f));
      ((uint2*)xo32)[(long)(nb + k) * 16 + cl] = o;
    }
  }
}

// ---------------- FM head: 4 graphs per block, V streamed once per block ----------------
__global__ __launch_bounds__(384) void k_fm(
    const float* __restrict__ xfm, const float* __restrict__ V,
    const float* __restrict__ fw, const float* __restrict__ bu,
    const float* __restrict__ bi, const float* __restrict__ b0,
    const int* __restrict__ uid, const int* __restrict__ iid,
    float* __restrict__ out){
  __shared__ float xsh[4][384];
  __shared__ float xsq[4][384];
  __shared__ float part[4][384];
  int j = threadIdx.x;                 // 0..383 = FM column
  int g0 = blockIdx.x * 4;
#pragma unroll
  for (int b = 0; b < 4; b++){
    float xv_ = xfm[(g0 + b) * 384 + j];
    xsh[b][j] = xv_;
    xsq[b][j] = xv_ * xv_;
  }
  __syncthreads();
  float xv[4] = {0.f, 0.f, 0.f, 0.f};
  float vv[4] = {0.f, 0.f, 0.f, 0.f};
  for (int k = 0; k < 384; k++){
    float v = V[(size_t)k * 384 + j];
    float v2 = v * v;
#pragma unroll
    for (int b = 0; b < 4; b++){
      xv[b] = fmaf(xsh[b][k], v, xv[b]);
      vv[b] = fmaf(xsq[b][k], v2, vv[b]);
    }
  }
  float fwj = fw[j];
#pragma unroll
  for (int b = 0; b < 4; b++)
    part[b][j] = 0.5f * (xv[b] * xv[b] - vv[b]) + xsh[b][j] * fwj;
  __syncthreads();
  int w = j >> 6, lane = j & 63;
  if (w < 4){
    float s = part[w][lane] + part[w][lane + 64] + part[w][lane + 128] +
              part[w][lane + 192] + part[w][lane + 256] + part[w][lane + 320];
    s = wsum(s);
    if (lane == 0){
      int b = g0 + w;
      out[b] = s + bu[uid[b]] + bi[iid[b]] + b0[0];
    }
  }
}

extern "C" void kernel_launch(void* const* d_in, const int* in_sizes, int n_in,
                              void* d_out, int out_size, void* d_ws, size_t ws_size,
                              hipStream_t stream) {
  const int* uid      = (const int*)d_in[0];
  const int* iid      = (const int*)d_in[1];
  const int* u_nodes  = (const int*)d_in[2];
  const int* i_nodes  = (const int*)d_in[3];
  const int* u_ei     = (const int*)d_in[4];
  const int* i_ei     = (const int*)d_in[5];
  const int* u_et     = (const int*)d_in[6];
  const int* i_et     = (const int*)d_in[7];
  const float* user_emb = (const float*)d_in[10];
  const float* item_emb = (const float*)d_in[11];
  const float* word_emb = (const float*)d_in[12];
  const float* trans_u_W = (const float*)d_in[13];
  const float* trans_u_b = (const float*)d_in[14];
  const float* trans_i_W = (const float*)d_in[15];
  const float* trans_i_b = (const float*)d_in[16];
  const float* trans_w_W = (const float*)d_in[17];
  const float* trans_w_b = (const float*)d_in[18];
  const float* inter_u_W = (const float*)d_in[19];
  const float* inter_u_b = (const float*)d_in[20];
  const float* inter_i_W = (const float*)d_in[21];
  const float* inter_i_b = (const float*)d_in[22];
  const float* conv_u_W  = (const float*)d_in[23];
  const float* conv_u_b  = (const float*)d_in[24];
  const float* conv_u_att= (const float*)d_in[25];
  const float* conv_u_rel= (const float*)d_in[26];
  const float* conv_i_W  = (const float*)d_in[27];
  const float* conv_i_b  = (const float*)d_in[28];
  const float* conv_i_att= (const float*)d_in[29];
  const float* conv_i_rel= (const float*)d_in[30];
  const float* pool_W    = (const float*)d_in[31];
  const float* fm_w      = (const float*)d_in[32];
  const float* fm_V      = (const float*)d_in[33];
  const float* fm_bias_u = (const float*)d_in[34];
  const float* fm_bias_i = (const float*)d_in[35];
  const float* fm_bias   = (const float*)d_in[36];
  float* out = (float*)d_out;
  int nwords32 = in_sizes[12] / 2;   // fp32 elements / 2 = packed uints
  int wconvB = (nwords32 + 255) / 256;

  // workspace carve-up (all chunks multiples of 16 B)
  char* w = (char*)d_ws;
  short* X0   = (short*)w;          w += (size_t)2 * NN * 64 * 2;   // 32 MB
  short* X1   = (short*)w;          w += (size_t)2 * NN * 64 * 2;   // 32 MB
  short* H    = (short*)w;          w += (size_t)2 * NN * 64 * 2;   // 32 MB
  short* wtab = (short*)w;          w += (size_t)in_sizes[12] * 2;  // bf16 word table
  int* pedge  = (int*)w;            w += (size_t)2 * NE * 4;        // 4 MB
  float* a0   = (float*)w;          w += (size_t)2 * NN * 4;
  float* a1   = (float*)w;          w += (size_t)2 * NN * 4;
  int* rowptr = (int*)w;            w += (size_t)(2 * NN + 256) * 4;
  int* cursor = (int*)w;            w += (size_t)2 * NN * 4;
  int* cnt    = (int*)w;            w += (size_t)2 * NN * 4;
  int* bsum   = (int*)w;            w += 1024 * 4;
  short8* frag = (short8*)w;        w += (size_t)5 * 512 * 16;      // 5 matrices
  float* waA  = (float*)w;          w += 2 * 2 * 2 * 64 * 4;
  float* ba   = (float*)w;          w += 64;
  float* rtab = (float*)w;          w += 64;
  float* qbuf = (float*)w;          w += (size_t)4 * NB * 64 * 4;
  float* xfm  = (float*)w;          w += (size_t)NB * 384 * 4;

  int megaB = 12 + wconvB + 2 * NN / 256 + 2 * NB / 4;
  k_mega   <<<megaB, 256, 0, stream>>>(wconvB, word_emb, (unsigned*)wtab, nwords32,
                                       cnt,
                                       conv_u_W, conv_i_W, pool_W, conv_u_b, conv_i_b,
                                       conv_u_att, conv_i_att, conv_u_rel, conv_i_rel,
                                       frag, waA, ba, rtab,
                                       uid, iid, user_emb, item_emb,
                                       inter_u_W, inter_u_b, inter_i_W, inter_i_b,
                                       trans_u_W, trans_u_b, trans_i_W, trans_i_b,
                                       xfm, qbuf);
  k_hist   <<<8 * (2 * NE / 256), 256, 0, stream>>>(u_ei, i_ei, cnt);
  k_scan1  <<<2 * NN / 256, 256, 0, stream>>>(cnt, rowptr, bsum);
  k_scan2  <<<1, 1024, 0, stream>>>(bsum);
  k_scan3  <<<2 * NN / 256, 256, 0, stream>>>(rowptr, bsum, cursor);
  k_scatter<<<8 * (2 * NE / 256), 256, 0, stream>>>(u_ei, i_ei, u_et, i_et,
                                                    cursor, pedge);

  // layer 0
  k_gemm_h<<<2 * NN / 128, 256, 0, stream>>>(X0, wtab, u_nodes, i_nodes, frag,
                                             conv_u_b, conv_i_b, 0,
                                             waA, ba, H, a0, a1);
  k_agg   <<<2 * NN / 32, 256, 0, stream>>>(rowptr, pedge, a0, a1, rtab, 0,
                                            (const unsigned*)H, (unsigned*)X0);
  // gemm_h(l=1) + scorepool(l=0) co-dispatch
  k_gsp   <<<2 * NN / 128 + 2 * NB, 256, 0, stream>>>(X0, wtab, u_nodes, i_nodes,
                                                      frag, conv_u_b, conv_i_b,
                                                      waA, ba, H, a0, a1,
                                                      qbuf, trans_w_W, trans_w_b, xfm);
  k_agg   <<<2 * NN / 32, 256, 0, stream>>>(rowptr, pedge, a0, a1, rtab, 1,
                                            (const unsigned*)H, (unsigned*)X1);
  k_scorepool<<<2 * NB, 256, 0, stream>>>(X1, frag, qbuf, 1,
                                          trans_w_W, trans_w_b, xfm);
  k_fm<<<NB / 4, 384, 0, stream>>>(xfm, fm_V, fm_w, fm_bias_u, fm_bias_i, fm_bias,
                                   uid, iid, out);
}

// Round 9
// 462.490 us; speedup vs baseline: 1.2280x; 1.0013x over previous
//
#include <hip/hip_runtime.h>
#include <hip/hip_bf16.h>

#define NN 131072   // nodes per side
#define NE 524288   // edges per side
#define NB 1024     // batch (graphs per side)

typedef __attribute__((ext_vector_type(8))) short short8;   // 8 bf16
typedef __attribute__((ext_vector_type(4))) float f32x4;

__device__ __forceinline__ float wsum(float v){
#pragma unroll
  for (int o = 32; o > 0; o >>= 1) v += __shfl_xor(v, o, 64);
  return v;
}
__device__ __forceinline__ short f2bs(float f){
  __hip_bfloat16 t = __float2bfloat16(f);
  union { __hip_bfloat16 b; short s; } u; u.b = t; return u.s;
}
__device__ __forceinline__ float bs2f(short s){
  return __uint_as_float(((unsigned)(unsigned short)s) << 16);
}
__device__ __forceinline__ float ulo2f(unsigned v){ return __uint_as_float(v << 16); }
__device__ __forceinline__ float uhi2f(unsigned v){ return __uint_as_float(v & 0xFFFF0000u); }
__device__ __forceinline__ unsigned fpack(float x, float y){
  return (unsigned)(unsigned short)f2bs(x) | ((unsigned)(unsigned short)f2bs(y) << 16);
}

// ---------------- mega: XCD-hist | frag pack | waA/ba/rtab | wconv | prep ----------------
__global__ void k_mega(int wconvB,
                       const int* __restrict__ u_ei, const int* __restrict__ i_ei,
                       int* __restrict__ cnt,
                       const float* __restrict__ wemb, unsigned* __restrict__ wtab,
                       int n32,
                       const float* __restrict__ cuW, const float* __restrict__ ciW,
                       const float* __restrict__ pW,
                       const float* __restrict__ cub, const float* __restrict__ cib,
                       const float* __restrict__ uatt, const float* __restrict__ iatt,
                       const float* __restrict__ urel, const float* __restrict__ irel,
                       short8* __restrict__ frag, float* __restrict__ waA,
                       float* __restrict__ ba, float* __restrict__ rtab,
                       const int* __restrict__ uid, const int* __restrict__ iid,
                       const float* __restrict__ uemb, const float* __restrict__ iemb,
                       const float* __restrict__ uiW, const float* __restrict__ uib,
                       const float* __restrict__ iiW, const float* __restrict__ iib,
                       const float* __restrict__ utW, const float* __restrict__ utb,
                       const float* __restrict__ itW, const float* __restrict__ itb,
                       float* __restrict__ xfm, float* __restrict__ q){
  const int histB = 8 * (2 * NE / 256);
  int blk = blockIdx.x, tid = threadIdx.x;
  if (blk < histB){
    // XCD-partitioned histogram (cnt pre-zeroed by hipMemsetAsync)
    int x = blk & 7;
    int ee = (blk >> 3) * 256 + tid;
    int side = ee >= NE;
    int e = ee - side * NE;
    const int* ei = side ? i_ei : u_ei;
    int dst = ei[NE + e] + side * NN;
    if ((dst >> 15) == x) atomicAdd(&cnt[dst], 1);
  } else if (blk < histB + 10){
    int b2 = blk - histB;
    int mat = b2 >> 1;
    const float* W = mat < 2 ? cuW + mat * 4096 : (mat < 4 ? ciW + (mat - 2) * 4096 : pW);
    int g = (b2 & 1) * 256 + tid;     // [0,512)
    int lane = g & 63, rest = g >> 6;
    int hh = rest & 1, t = rest >> 1;
    int m = lane & 15, qq = lane >> 4;
    short8 v;
#pragma unroll
    for (int j = 0; j < 8; j++)
      v[j] = f2bs(W[(hh * 32 + qq * 8 + j) * 64 + (t * 16 + m)]);
    frag[mat * 512 + g] = v;
  } else if (blk < histB + 12){
    int side = blk - histB - 10;
    const float* W    = side ? ciW : cuW;
    const float* bias = side ? cib : cub;
    const float* att  = side ? iatt : uatt;
    const float* rel  = side ? irel : urel;
    int l = tid >> 7, a = (tid >> 6) & 1, kk = tid & 63;
    float s = 0.f;
    for (int c = 0; c < 64; c++) s += W[l * 4096 + kk * 64 + c] * att[l * 192 + a * 64 + c];
    waA[((side * 2 + l) * 2 + a) * 64 + kk] = s;
    if (tid < 4){
      int l2 = tid >> 1, a2 = tid & 1;
      float sb = 0.f;
      for (int c = 0; c < 64; c++) sb += bias[l2 * 64 + c] * att[l2 * 192 + a2 * 64 + c];
      ba[(side * 2 + l2) * 2 + a2] = sb;
    }
    if (tid >= 4 && tid < 12){
      int id = tid - 4, l2 = id >> 2, tt = id & 3;
      float sr = 0.f;
      for (int c = 0; c < 64; c++) sr += rel[l2 * 256 + tt * 64 + c] * att[l2 * 192 + 128 + c];
      rtab[(side * 2 + l2) * 4 + tt] = sr;
    }
  } else if (blk < histB + 12 + wconvB){
    int id = (blk - histB - 12) * 256 + tid;
    if (id < n32){
      const float2* src = (const float2*)wemb;
      float2 v = src[id];
      wtab[id] = fpack(v.x, v.y);
    }
  } else {
    int lane = tid & 63, w = tid >> 6;
    int b = (blk - histB - 12 - wconvB) * 4 + w;   // [0, 2NB)
    int side = b >= NB;
    int lb = b - side * NB;
    const int* ids = side ? iid : uid;
    const float* emb = side ? iemb : uemb;
    const float* interW = side ? iiW : uiW;
    const float* interB = side ? iib : uib;
    const float* transW = side ? itW : utW;
    const float* transB = side ? itb : utb;
    int repOff = side ? 192 : 0;
    float xe = emb[(long)ids[lb] * 64 + lane];
    float o = interB[lane];
#pragma unroll
    for (int k = 0; k < 64; k++) o += __shfl(xe, k, 64) * interW[k * 64 + lane];
    xfm[lb * 384 + repOff + lane] = fmaxf(o, 0.f);
    for (int l = 0; l < 2; l++){
      float t = transB[l * 64 + lane];
#pragma unroll
      for (int k = 0; k < 64; k++) t += __shfl(xe, k, 64) * transW[l * 4096 + k * 64 + lane];
      q[((size_t)(side * 2 + l) * NB + lb) * 64 + lane] = fmaxf(t, 0.f);
    }
  }
}

__global__ void k_scan1(const int* __restrict__ cnt, int* __restrict__ rowptr,
                        int* __restrict__ bsum){
  __shared__ int sh[256];
  int i = blockIdx.x * 256 + threadIdx.x;
  int v = cnt[i];
  sh[threadIdx.x] = v; __syncthreads();
  for (int off = 1; off < 256; off <<= 1){
    int t = (threadIdx.x >= off) ? sh[threadIdx.x - off] : 0;
    __syncthreads();
    sh[threadIdx.x] += t;
    __syncthreads();
  }
  int incl = sh[threadIdx.x];
  rowptr[i] = incl - v;
  if (threadIdx.x == 255) bsum[blockIdx.x] = incl;
}

__global__ void k_scan2(int* __restrict__ bsum){
  __shared__ int sh[1024];
  int v = bsum[threadIdx.x];
  sh[threadIdx.x] = v; __syncthreads();
  for (int off = 1; off < 1024; off <<= 1){
    int t = (threadIdx.x >= off) ? sh[threadIdx.x - off] : 0;
    __syncthreads();
    sh[threadIdx.x] += t;
    __syncthreads();
  }
  bsum[threadIdx.x] = sh[threadIdx.x] - v;  // exclusive
}

__global__ void k_scan3(int* __restrict__ rowptr, const int* __restrict__ bsum,
                        int* __restrict__ cursor){
  int i = blockIdx.x * 256 + threadIdx.x;
  int v = rowptr[i] + bsum[blockIdx.x];
  rowptr[i] = v;
  cursor[i] = v;
  if (i == 0) rowptr[2 * NN] = 2 * NE;
}

// ---------------- scatter (XCD-partitioned) | word-level a0/a1 tables ----------------
__global__ void k_scw(const int* __restrict__ u_ei, const int* __restrict__ i_ei,
                      const int* __restrict__ u_et, const int* __restrict__ i_et,
                      int* __restrict__ cursor, int* __restrict__ pedge,
                      const short* __restrict__ wtab, int nwords,
                      const float* __restrict__ waA, const float* __restrict__ ba,
                      float* __restrict__ wa0, float* __restrict__ wa1){
  const int scatB = 8 * (2 * NE / 256);
  int blk = blockIdx.x, tid = threadIdx.x;
  if (blk < scatB){
    int x = blk & 7;
    int ee = (blk >> 3) * 256 + tid;
    int side = ee >= NE;
    int e = ee - side * NE;
    const int* ei = side ? i_ei : u_ei;
    int dst = ei[NE + e] + side * NN;
    if ((dst >> 15) == x){
      const int* et = side ? i_et : u_et;
      int src = ei[e] + side * NN;
      int p = atomicAdd(&cursor[dst], 1);
      pedge[p] = src | (et[e] << 18);
    }
  } else {
    // wa0/wa1[side][word] = wtab[word] . waA(side,l=0,a) + ba
    int lane = tid & 63, w = tid >> 6;
    int q = lane >> 4, cl = lane & 15;
    int sw0 = ((blk - scatB) * 4 + w) * 8;
    const uint2* wt2 = (const uint2*)wtab;
    for (int it = 0; it < 2; it++){
      int wj = sw0 + it * 4 + q;
      if (wj >= 2 * nwords) continue;
      int side = wj >= nwords;
      int wid = wj - side * nwords;
      const float* A0 = waA + (side * 2 + 0) * 2 * 64;
      const float* A1 = A0 + 64;
      uint2 v = wt2[(long)wid * 16 + cl];
      int d = 4 * cl;
      float p0 = ulo2f(v.x) * A0[d] + uhi2f(v.x) * A0[d + 1] +
                 ulo2f(v.y) * A0[d + 2] + uhi2f(v.y) * A0[d + 3];
      float p1 = ulo2f(v.x) * A1[d] + uhi2f(v.x) * A1[d + 1] +
                 ulo2f(v.y) * A1[d + 2] + uhi2f(v.y) * A1[d + 3];
      p0 += __shfl_xor(p0, 1, 64); p0 += __shfl_xor(p0, 2, 64);
      p0 += __shfl_xor(p0, 4, 64); p0 += __shfl_xor(p0, 8, 64);
      p1 += __shfl_xor(p1, 1, 64); p1 += __shfl_xor(p1, 2, 64);
      p1 += __shfl_xor(p1, 4, 64); p1 += __shfl_xor(p1, 8, 64);
      if (cl == 0){
        wa0[(size_t)side * nwords + wid] = p0 + ba[side * 4 + 0];
        wa1[(size_t)side * nwords + wid] = p1 + ba[side * 4 + 1];
      }
    }
  }
}

// ---------------- aggregation: xagg[dst] = sum_e softmax(e) * x[src_e] (no relu) ----------------
template<int L>
__device__ __forceinline__ void dev_agg(
    const int* __restrict__ rowptr, const int* __restrict__ pedge,
    const float* __restrict__ a0, const float* __restrict__ a1,        // L==1
    const float* __restrict__ wa0, const float* __restrict__ wa1,      // L==0
    const int* __restrict__ u_nodes, const int* __restrict__ i_nodes, int nwords,
    const float* __restrict__ rtab, const short* __restrict__ rows,
    unsigned* __restrict__ xo32){
  int lane = threadIdx.x & 63, w = threadIdx.x >> 6;
  int nb = (blockIdx.x * 4 + w) * 8;              // 8 nodes per wave
  int side = nb >= NN;
  const float* rt = rtab + (side * 2 + L) * 4;
  float rt0 = rt[0], rt1 = rt[1], rt2 = rt[2], rt3 = rt[3];
  const int* nodesS = side ? i_nodes : u_nodes;
  const float* wa0S = wa0 + (size_t)side * nwords;
  const float* wa1S = wa1 + (size_t)side * nwords;
  int q = lane >> 4, cl = lane & 15;
  int rp = (lane < 9) ? rowptr[nb + lane] : 0;
  float a1v = 0.f;
  if (L == 0){
    if (lane < 8) a1v = wa1S[nodesS[nb + lane - side * NN]];
  } else {
    if (lane < 8) a1v = a1[nb + lane];
  }
  int rp0 = __shfl(rp, 0, 64);
  int rp8 = __shfl(rp, 8, 64);
  int tot = min(rp8 - rp0, 64);
  // coalesced preload of the wave's edge window + softmax numerator
  int eidx = rp0 + lane;
  int pe = (lane < tot) ? pedge[eidx] : 0;
  int psrc = pe & 0x3FFFF;
  int prow; float pa0 = 0.f;
  if (L == 0){
    int wid = (lane < tot) ? nodesS[psrc - side * NN] : 0;
    prow = wid;
    if (lane < tot) pa0 = wa0S[wid];
  } else {
    prow = psrc;
    if (lane < tot) pa0 = a0[psrc];
  }
  int kn = 0;
#pragma unroll
  for (int t = 1; t < 8; t++)
    kn += (eidx >= __shfl(rp, t, 64)) ? 1 : 0;
  float a1n = __shfl(a1v, kn, 64);
  int pet = (pe >> 18) & 3;
  float rr = (pet & 2) ? ((pet & 1) ? rt3 : rt2) : ((pet & 1) ? rt1 : rt0);
  float vv = pa0 + a1n + rr;
  vv = (vv > 0.f) ? vv : 0.2f * vv;
  float pex = (lane < tot) ? __expf(vv) : 0.f;
  const uint2* h2 = (const uint2*)rows;
#pragma unroll
  for (int k = 0; k < 8; k++){
    int r0 = __shfl(rp, k, 64), r1 = __shfl(rp, k + 1, 64);
    float a1k = __shfl(a1v, k, 64);
    float ax0 = 0.f, ay0 = 0.f, ax1 = 0.f, ay1 = 0.f, den = 0.f;
    for (int j = r0; j < r1; j += 4){
      int e = j + q;
      bool ok = e < r1;
      int idx = e - rp0;
      int idxc = min(idx, 63);
      int s = __shfl(prow, idxc, 64);
      float ex = __shfl(pex, idxc, 64);
      if (idx >= 64 && ok){           // rare spill past preload window
        int pe2 = pedge[e];
        int s2 = pe2 & 0x3FFFF;
        int et2 = (pe2 >> 18) & 3;
        float r2 = (et2 & 2) ? ((et2 & 1) ? rt3 : rt2) : ((et2 & 1) ? rt1 : rt0);
        float av;
        if (L == 0){ int wid = nodesS[s2 - side * NN]; av = wa0S[wid]; s = wid; }
        else       { av = a0[s2]; s = s2; }
        float v2 = av + a1k + r2;
        v2 = (v2 > 0.f) ? v2 : 0.2f * v2;
        ex = __expf(v2);
      }
      if (ok){
        uint2 v = h2[(long)s * 16 + cl];
        ax0 += ex * ulo2f(v.x); ay0 += ex * uhi2f(v.x);
        ax1 += ex * ulo2f(v.y); ay1 += ex * uhi2f(v.y);
        den += ex;
      }
    }
    ax0 += __shfl_xor(ax0, 16, 64); ax0 += __shfl_xor(ax0, 32, 64);
    ay0 += __shfl_xor(ay0, 16, 64); ay0 += __shfl_xor(ay0, 32, 64);
    ax1 += __shfl_xor(ax1, 16, 64); ax1 += __shfl_xor(ax1, 32, 64);
    ay1 += __shfl_xor(ay1, 16, 64); ay1 += __shfl_xor(ay1, 32, 64);
    den += __shfl_xor(den, 16, 64); den += __shfl_xor(den, 32, 64);
    float inv = 1.f / (den + 1e-16f);
    if (q == 0){
      uint2 o;
      o.x = fpack(ax0 * inv, ay0 * inv);
      o.y = fpack(ax1 * inv, ay1 * inv);
      ((uint2*)xo32)[(long)(nb + k) * 16 + cl] = o;
    }
  }
}

__global__ __launch_bounds__(256) void k_agg0(
    const int* __restrict__ rowptr, const int* __restrict__ pedge,
    const float* __restrict__ wa0, const float* __restrict__ wa1,
    const int* __restrict__ u_nodes, const int* __restrict__ i_nodes, int nwords,
    const float* __restrict__ rtab, const short* __restrict__ wtab,
    unsigned* __restrict__ xo32){
  dev_agg<0>(rowptr, pedge, nullptr, nullptr, wa0, wa1, u_nodes, i_nodes, nwords,
             rtab, wtab, xo32);
}

__global__ __launch_bounds__(256) void k_agg1(
    const int* __restrict__ rowptr, const int* __restrict__ pedge,
    const float* __restrict__ a0, const float* __restrict__ a1,
    const float* __restrict__ rtab, const short* __restrict__ x,
    unsigned* __restrict__ xo32){
  dev_agg<1>(rowptr, pedge, a0, a1, nullptr, nullptr, nullptr, nullptr, 0,
             rtab, x, xo32);
}

// ---------------- fused post: x=relu(xagg@W+b); gates; gmp; trans_w; gated X1 + a0/a1 ----------------
__global__ __launch_bounds__(256) void k_gp(
    int l, const short* __restrict__ xagg, const short8* __restrict__ frag,
    const float* __restrict__ cub, const float* __restrict__ cib,
    const float* __restrict__ waA_all, const float* __restrict__ ba_all,
    const float* __restrict__ qbuf, const float* __restrict__ twW_all,
    const float* __restrict__ twb_all, float* __restrict__ xfm,
    short* __restrict__ xnext, float* __restrict__ a0, float* __restrict__ a1){
  __shared__ short xt[128 * 72];       // padded rows (72 shorts) for bank spread
  __shared__ float gates[128];
  __shared__ float red[4][64];
  int b = blockIdx.x;                  // [0, 2NB)
  int side = b >= NB;
  int g = b - side * NB;
  long base = (long)side * NN + (long)g * 128;
  int tid = threadIdx.x, lane = tid & 63, w = tid >> 6;
  int m = lane & 15, q = lane >> 4;
  // stage A: conv GEMM
  const short8* wfrag = frag + (side * 2 + l) * 512;
  const float* bias = (side ? cib : cub) + l * 64;
  short8 Bf[4][2];
#pragma unroll
  for (int t = 0; t < 4; t++)
#pragma unroll
    for (int hh = 0; hh < 2; hh++)
      Bf[t][hh] = wfrag[(t * 2 + hh) * 64 + lane];
  float bs[4];
#pragma unroll
  for (int t = 0; t < 4; t++) bs[t] = bias[t * 16 + m];
  f32x4 accA[2][4];
#pragma unroll
  for (int rb = 0; rb < 2; rb++){
    long n0 = base + w * 32 + rb * 16;
    const short8* xr = (const short8*)(xagg + (n0 + m) * 64);
    short8 A0 = xr[q];
    short8 A1 = xr[q + 4];
#pragma unroll
    for (int t = 0; t < 4; t++){
      f32x4 acc = (f32x4){bs[t], bs[t], bs[t], bs[t]};
      acc = __builtin_amdgcn_mfma_f32_16x16x32_bf16(A0, Bf[t][0], acc, 0, 0, 0);
      acc = __builtin_amdgcn_mfma_f32_16x16x32_bf16(A1, Bf[t][1], acc, 0, 0, 0);
#pragma unroll
      for (int r = 0; r < 4; r++) acc[r] = fmaxf(acc[r], 0.f);
      accA[rb][t] = acc;
#pragma unroll
      for (int r = 0; r < 4; r++)
        xt[(w * 32 + rb * 16 + q * 4 + r) * 72 + t * 16 + m] = f2bs(acc[r]);
    }
  }
  __syncthreads();
  // stage B: pool GEMM from LDS -> gates
  const short8* pfrag = frag + 4 * 512;
  const float* qv_ = qbuf + ((size_t)(side * 2 + l) * NB + g) * 64;
  short8 Pf[4][2];
#pragma unroll
  for (int t = 0; t < 4; t++)
#pragma unroll
    for (int hh = 0; hh < 2; hh++)
      Pf[t][hh] = pfrag[(t * 2 + hh) * 64 + lane];
  float qv[4];
#pragma unroll
  for (int t = 0; t < 4; t++) qv[t] = qv_[t * 16 + m];
#pragma unroll
  for (int rb = 0; rb < 2; rb++){
    int rowb = w * 32 + rb * 16;
    short8 A0 = *(const short8*)(xt + (rowb + m) * 72 + q * 8);
    short8 A1 = *(const short8*)(xt + (rowb + m) * 72 + 32 + q * 8);
    f32x4 accp[4];
#pragma unroll
    for (int t = 0; t < 4; t++){
      accp[t] = (f32x4){0.f, 0.f, 0.f, 0.f};
      accp[t] = __builtin_amdgcn_mfma_f32_16x16x32_bf16(A0, Pf[t][0], accp[t], 0, 0, 0);
      accp[t] = __builtin_amdgcn_mfma_f32_16x16x32_bf16(A1, Pf[t][1], accp[t], 0, 0, 0);
    }
#pragma unroll
    for (int r = 0; r < 4; r++){
      float p = accp[0][r] * qv[0] + accp[1][r] * qv[1] +
                accp[2][r] * qv[2] + accp[3][r] * qv[3];
      p += __shfl_xor(p, 1, 64); p += __shfl_xor(p, 2, 64);
      p += __shfl_xor(p, 4, 64); p += __shfl_xor(p, 8, 64);
      if (m == 0)
        gates[rowb + q * 4 + r] = 1.f / (1.f + __expf(-p * 0.125f));
    }
  }
  __syncthreads();
  // gated max pool
  const unsigned* xt32 = (const unsigned*)xt;
  int c = lane & 31, half = lane >> 5;
  float mxx = 0.f, mxy = 0.f;
#pragma unroll
  for (int p = 0; p < 16; p++){
    int nn = w * 32 + 2 * p + half;
    unsigned v = xt32[nn * 36 + c];
    float gt = gates[nn];
    mxx = fmaxf(mxx, ulo2f(v) * gt);
    mxy = fmaxf(mxy, uhi2f(v) * gt);
  }
  mxx = fmaxf(mxx, __shfl_xor(mxx, 32, 64));
  mxy = fmaxf(mxy, __shfl_xor(mxy, 32, 64));
  if (half == 0){ red[w][2 * c] = mxx; red[w][2 * c + 1] = mxy; }
  __syncthreads();
  if (tid < 64){
    const float* twW = twW_all + l * 4096;
    const float* twb = twb_all + l * 64;
    int off = (side ? 256 : 64) + l * 64;
    float p = fmaxf(fmaxf(red[0][tid], red[1][tid]), fmaxf(red[2][tid], red[3][tid]));
    float o = twb[tid];
    red[0][tid] = p;
    __syncwarp();
    for (int d = 0; d < 64; d++) o += red[0][d] * twW[d * 64 + tid];
    xfm[g * 384 + off + tid] = fmaxf(o, 0.f);
  }
  if (l == 0){
    // gated next-layer input write (coalesced via LDS)
#pragma unroll
    for (int p = 0; p < 4; p++){
      int row = p * 32 + (tid >> 3);
      int col8 = (tid & 7) * 8;
      float gt = gates[row];
      short8 v = *(const short8*)(xt + row * 72 + col8);
      short8 o;
#pragma unroll
      for (int j = 0; j < 8; j++) o[j] = f2bs(bs2f(v[j]) * gt);
      *(short8*)(xnext + (base + row) * 64 + col8) = o;
    }
    // next-layer a0/a1 from gated x_next: a = g*(x.waA1) + ba1
    const float* wn0p = waA_all + ((side * 2 + 1) * 2 + 0) * 64;
    const float* wn1p = wn0p + 64;
    float wn0[4], wn1[4];
#pragma unroll
    for (int t = 0; t < 4; t++){ wn0[t] = wn0p[t * 16 + m]; wn1[t] = wn1p[t * 16 + m]; }
    float ban0 = ba_all[(side * 2 + 1) * 2 + 0];
    float ban1 = ba_all[(side * 2 + 1) * 2 + 1];
#pragma unroll
    for (int rb = 0; rb < 2; rb++)
#pragma unroll
      for (int r = 0; r < 4; r++){
        float p0 = accA[rb][0][r] * wn0[0] + accA[rb][1][r] * wn0[1] +
                   accA[rb][2][r] * wn0[2] + accA[rb][3][r] * wn0[3];
        float p1 = accA[rb][0][r] * wn1[0] + accA[rb][1][r] * wn1[1] +
                   accA[rb][2][r] * wn1[2] + accA[rb][3][r] * wn1[3];
        p0 += __shfl_xor(p0, 1, 64); p0 += __shfl_xor(p0, 2, 64);
        p0 += __shfl_xor(p0, 4, 64); p0 += __shfl_xor(p0, 8, 64);
        p1 += __shfl_xor(p1, 1, 64); p1 += __shfl_xor(p1, 2, 64);
        p1 += __shfl_xor(p1, 4, 64); p1 += __shfl_xor(p1, 8, 64);
        if (m == 0){
          int row = w * 32 + rb * 16 + q * 4 + r;
          float gr = gates[row];
          a0[base + row] = p0 * gr + ban0;
          a1[base + row] = p1 * gr + ban1;
        }
      }
  }
}

// ---------------- FM head: 4 graphs per block, V streamed once per block ----------------
__global__ __launch_bounds__(384) void k_fm(
    const float* __restrict__ xfm, const float* __restrict__ V,
    const float* __restrict__ fw, const float* __restrict__ bu,
    const float* __restrict__ bi, const float* __restrict__ b0,
    const int* __restrict__ uid, const int* __restrict__ iid,
    float* __restrict__ out){
  __shared__ float xsh[4][384];
  __shared__ float xsq[4][384];
  __shared__ float part[4][384];
  int j = threadIdx.x;
  int g0 = blockIdx.x * 4;
#pragma unroll
  for (int b = 0; b < 4; b++){
    float xv_ = xfm[(g0 + b) * 384 + j];
    xsh[b][j] = xv_;
    xsq[b][j] = xv_ * xv_;
  }
  __syncthreads();
  float xv[4] = {0.f, 0.f, 0.f, 0.f};
  float vv[4] = {0.f, 0.f, 0.f, 0.f};
  for (int k = 0; k < 384; k++){
    float v = V[(size_t)k * 384 + j];
    float v2 = v * v;
#pragma unroll
    for (int b = 0; b < 4; b++){
      xv[b] = fmaf(xsh[b][k], v, xv[b]);
      vv[b] = fmaf(xsq[b][k], v2, vv[b]);
    }
  }
  float fwj = fw[j];
#pragma unroll
  for (int b = 0; b < 4; b++)
    part[b][j] = 0.5f * (xv[b] * xv[b] - vv[b]) + xsh[b][j] * fwj;
  __syncthreads();
  int w = j >> 6, lane = j & 63;
  if (w < 4){
    float s = part[w][lane] + part[w][lane + 64] + part[w][lane + 128] +
              part[w][lane + 192] + part[w][lane + 256] + part[w][lane + 320];
    s = wsum(s);
    if (lane == 0){
      int b = g0 + w;
      out[b] = s + bu[uid[b]] + bi[iid[b]] + b0[0];
    }
  }
}

extern "C" void kernel_launch(void* const* d_in, const int* in_sizes, int n_in,
                              void* d_out, int out_size, void* d_ws, size_t ws_size,
                              hipStream_t stream) {
  const int* uid      = (const int*)d_in[0];
  const int* iid      = (const int*)d_in[1];
  const int* u_nodes  = (const int*)d_in[2];
  const int* i_nodes  = (const int*)d_in[3];
  const int* u_ei     = (const int*)d_in[4];
  const int* i_ei     = (const int*)d_in[5];
  const int* u_et     = (const int*)d_in[6];
  const int* i_et     = (const int*)d_in[7];
  const float* user_emb = (const float*)d_in[10];
  const float* item_emb = (const float*)d_in[11];
  const float* word_emb = (const float*)d_in[12];
  const float* trans_u_W = (const float*)d_in[13];
  const float* trans_u_b = (const float*)d_in[14];
  const float* trans_i_W = (const float*)d_in[15];
  const float* trans_i_b = (const float*)d_in[16];
  const float* trans_w_W = (const float*)d_in[17];
  const float* trans_w_b = (const float*)d_in[18];
  const float* inter_u_W = (const float*)d_in[19];
  const float* inter_u_b = (const float*)d_in[20];
  const float* inter_i_W = (const float*)d_in[21];
  const float* inter_i_b = (const float*)d_in[22];
  const float* conv_u_W  = (const float*)d_in[23];
  const float* conv_u_b  = (const float*)d_in[24];
  const float* conv_u_att= (const float*)d_in[25];
  const float* conv_u_rel= (const float*)d_in[26];
  const float* conv_i_W  = (const float*)d_in[27];
  const float* conv_i_b  = (const float*)d_in[28];
  const float* conv_i_att= (const float*)d_in[29];
  const float* conv_i_rel= (const float*)d_in[30];
  const float* pool_W    = (const float*)d_in[31];
  const float* fm_w      = (const float*)d_in[32];
  const float* fm_V      = (const float*)d_in[33];
  const float* fm_bias_u = (const float*)d_in[34];
  const float* fm_bias_i = (const float*)d_in[35];
  const float* fm_bias   = (const float*)d_in[36];
  float* out = (float*)d_out;
  int n32 = in_sizes[12] / 2;          // packed uints in word table
  int nwords = in_sizes[12] / 64;      // words (HID=64)
  int wconvB = (n32 + 255) / 256;

  // workspace carve-up
  char* w = (char*)d_ws;
  short* X0   = (short*)w;          w += (size_t)2 * NN * 64 * 2;   // 32 MB
  short* X1   = (short*)w;          w += (size_t)2 * NN * 64 * 2;   // 32 MB
  short* wtab = (short*)w;          w += (size_t)in_sizes[12] * 2;  // bf16 word table
  int* pedge  = (int*)w;            w += (size_t)2 * NE * 4;
  float* a0   = (float*)w;          w += (size_t)2 * NN * 4;
  float* a1   = (float*)w;          w += (size_t)2 * NN * 4;
  float* wa0  = (float*)w;          w += (size_t)2 * nwords * 4;
  float* wa1  = (float*)w;          w += (size_t)2 * nwords * 4;
  int* rowptr = (int*)w;            w += (size_t)(2 * NN + 256) * 4;
  int* cursor = (int*)w;            w += (size_t)2 * NN * 4;
  int* cnt    = (int*)w;            w += (size_t)2 * NN * 4;
  int* bsum   = (int*)w;            w += 1024 * 4;
  short8* frag = (short8*)w;        w += (size_t)5 * 512 * 16;
  float* waA  = (float*)w;          w += 2 * 2 * 2 * 64 * 4;
  float* ba   = (float*)w;          w += 64;
  float* rtab = (float*)w;          w += 64;
  float* qbuf = (float*)w;          w += (size_t)4 * NB * 64 * 4;
  float* xfm  = (float*)w;          w += (size_t)NB * 384 * 4;

  hipMemsetAsync(cnt, 0, (size_t)2 * NN * 4, stream);

  int histB = 8 * (2 * NE / 256);
  int megaB = histB + 12 + wconvB + 2 * NB / 4;
  k_mega<<<megaB, 256, 0, stream>>>(wconvB, u_ei, i_ei, cnt,
                                    word_emb, (unsigned*)wtab, n32,
                                    conv_u_W, conv_i_W, pool_W, conv_u_b, conv_i_b,
                                    conv_u_att, conv_i_att, conv_u_rel, conv_i_rel,
                                    frag, waA, ba, rtab,
                                    uid, iid, user_emb, item_emb,
                                    inter_u_W, inter_u_b, inter_i_W, inter_i_b,
                                    trans_u_W, trans_u_b, trans_i_W, trans_i_b,
                                    xfm, qbuf);
  k_scan1<<<2 * NN / 256, 256, 0, stream>>>(cnt, rowptr, bsum);
  k_scan2<<<1, 1024, 0, stream>>>(bsum);
  k_scan3<<<2 * NN / 256, 256, 0, stream>>>(rowptr, bsum, cursor);
  int wgB = (2 * nwords + 31) / 32;
  k_scw<<<histB + wgB, 256, 0, stream>>>(u_ei, i_ei, u_et, i_et, cursor, pedge,
                                         wtab, nwords, waA, ba, wa0, wa1);

  // layer 0: aggregate straight from the word table
  k_agg0<<<2 * NN / 32, 256, 0, stream>>>(rowptr, pedge, wa0, wa1,
                                          u_nodes, i_nodes, nwords, rtab,
                                          wtab, (unsigned*)X0);
  k_gp  <<<2 * NB, 256, 0, stream>>>(0, X0, frag, conv_u_b, conv_i_b, waA, ba,
                                     qbuf, trans_w_W, trans_w_b, xfm, X1, a0, a1);
  // layer 1
  k_agg1<<<2 * NN / 32, 256, 0, stream>>>(rowptr, pedge, a0, a1, rtab,
                                          X1, (unsigned*)X0);
  k_gp  <<<2 * NB, 256, 0, stream>>>(1, X0, frag, conv_u_b, conv_i_b, waA, ba,
                                     qbuf, trans_w_W, trans_w_b, xfm,
                                     nullptr, nullptr, nullptr);

  k_fm<<<NB / 4, 384, 0, stream>>>(xfm, fm_V, fm_w, fm_bias_u, fm_bias_i, fm_bias,
                                   uid, iid, out);
}